// Round 1
// 608.323 us; speedup vs baseline: 1.2140x; 1.2140x over previous
//
#include <hip/hip_runtime.h>
#include <hip/hip_fp16.h>
#include <math.h>

#define NN 100000
#define EE 1600000
#define DD 128
#define NBUCK 196          // ceil(NN / 512) buckets of 512 dst nodes
#define NBLKP 196          // partition blocks, 8192 edges each (196*8192 >= EE)
#define EPB 8192           // edges per partition block

typedef _Float16 f16;
typedef f16 f16x8 __attribute__((ext_vector_type(8)));
typedef float f32x4 __attribute__((ext_vector_type(4)));

#define LDA 136            // padded LDS row stride in halves (272 B = 17*16)
#define WCHUNKS 2304       // 36864 B per W matrix image (128*136 halves + pad)

// ---------- bucketed CSR build ----------
__global__ __launch_bounds__(256) void part_hist_k(const int* __restrict__ dst, int* __restrict__ bcnt) {
    __shared__ int lc[NBUCK];
    int t = threadIdx.x, blk = blockIdx.x;
    if (t < NBUCK) lc[t] = 0;
    __syncthreads();
    int e0 = blk * EPB;
    for (int i = t; i < EPB; i += 256) {
        int e = e0 + i;
        if (e < EE) atomicAdd(&lc[dst[e] >> 9], 1);
    }
    __syncthreads();
    if (t < NBUCK) bcnt[t * NBLKP + blk] = lc[t];
}

__global__ __launch_bounds__(256) void scanBB_k(const int* __restrict__ bcnt, int* __restrict__ ebase,
                                                int* __restrict__ btot) {
    __shared__ int sh[256];
    int t = threadIdx.x, b = blockIdx.x;
    int c = (t < NBLKP) ? bcnt[b * NBLKP + t] : 0;
    sh[t] = c;
    __syncthreads();
    for (int off = 1; off < 256; off <<= 1) {
        int v = (t >= off) ? sh[t - off] : 0;
        __syncthreads();
        sh[t] += v;
        __syncthreads();
    }
    if (t < NBLKP) ebase[b * NBLKP + t] = sh[t] - c;  // exclusive
    if (t == 255) btot[b] = sh[255];
}

__global__ __launch_bounds__(256) void scanBT_k(const int* __restrict__ btot, int* __restrict__ bstart,
                                                int* __restrict__ offsets) {
    __shared__ int sh[256];
    int t = threadIdx.x;
    int c = (t < NBUCK) ? btot[t] : 0;
    sh[t] = c;
    __syncthreads();
    for (int off = 1; off < 256; off <<= 1) {
        int v = (t >= off) ? sh[t - off] : 0;
        __syncthreads();
        sh[t] += v;
        __syncthreads();
    }
    if (t < NBUCK) bstart[t] = sh[t] - c;
    if (t == 0) { bstart[NBUCK] = EE; offsets[NN] = EE; }
}

__global__ __launch_bounds__(256) void part_k(const int* __restrict__ src, const int* __restrict__ dst,
                                              const int* __restrict__ bstart, const int* __restrict__ ebase,
                                              int2* __restrict__ ebuf) {
    __shared__ int cur[NBUCK];
    int t = threadIdx.x, blk = blockIdx.x;
    if (t < NBUCK) cur[t] = bstart[t] + ebase[t * NBLKP + blk];
    __syncthreads();
    int e0 = blk * EPB;
    for (int i = t; i < EPB; i += 256) {
        int e = e0 + i;
        if (e < EE) {
            int s = src[e], d = dst[e];
            int p = atomicAdd(&cur[d >> 9], 1);
            ebuf[p] = make_int2(s, d);
        }
    }
}

__global__ __launch_bounds__(512) void bucket_sort_k(const int2* __restrict__ ebuf,
                                                     const int* __restrict__ bstart,
                                                     int* __restrict__ offsets,
                                                     int* __restrict__ ssrc,
                                                     int* __restrict__ sdst) {
    __shared__ int sh[512];
    __shared__ int cur[512];
    int t = threadIdx.x, b = blockIdx.x;
    int d0 = b << 9;
    int beg = bstart[b], end = bstart[b + 1];

    cur[t] = 0;
    __syncthreads();
    for (int e = beg + t; e < end; e += 512) atomicAdd(&cur[ebuf[e].y - d0], 1);
    __syncthreads();
    int c = cur[t];
    sh[t] = c;
    __syncthreads();
    for (int off = 1; off < 512; off <<= 1) {
        int v = (t >= off) ? sh[t - off] : 0;
        __syncthreads();
        sh[t] += v;
        __syncthreads();
    }
    int excl = sh[t] - c;
    if (d0 + t < NN) offsets[d0 + t] = beg + excl;
    cur[t] = beg + excl;
    __syncthreads();
    for (int e = beg + t; e < end; e += 512) {
        int2 ed = ebuf[e];
        int p = atomicAdd(&cur[ed.y - d0], 1);
        ssrc[p] = ed.x;
        sdst[p] = ed.y;
    }
}

// ---------------- W prep: transpose + fp16 round into LDS-image layout ----------------
// For each of 5 matrices: Wt[m][n*LDA + k] = (f16)W[k*128 + n]; image padded to WCHUNKS*16 B.
__global__ __launch_bounds__(256) void wprep_k(const float* __restrict__ W_in,
                                               const float* __restrict__ Wl,
                                               f16* __restrict__ Wt) {
    int m = blockIdx.x;  // 0..4
    const float* src = (m == 0) ? W_in : (Wl + (size_t)(m - 1) * DD * DD);
    f16* dst = Wt + (size_t)m * (WCHUNKS * 8);
    for (int q = 0; q < 64; ++q) {
        int idx = q * 256 + threadIdx.x;   // 0..16383  (= k*128 + n)
        int k = idx >> 7, n = idx & 127;
        dst[n * LDA + k] = (f16)src[idx];
    }
}

// ---------------- GEMM: Y = X @ W via split-fp16 MFMA ----------------
// BM=64 rows/block, 256 threads = 4 waves, each wave 16 rows x 128 cols.
// acc = Xh*Wh + Xl*Wh  (X split to two fp16 halves; W fp16-rounded once).
// MODE 0: Yf = leaky(X@W + bias, 0.01) fp32. MODE 1: Yh = fp16(X@W), alpha dots.
template <int MODE>
__global__ __launch_bounds__(256, 2) void gemm_k(const float* __restrict__ X,
                                                 const f16* __restrict__ Wt,
                                                 const float* __restrict__ bias,
                                                 const float* __restrict__ av_src,
                                                 const float* __restrict__ av_dst,
                                                 float* __restrict__ Yf,
                                                 __half* __restrict__ Yh,
                                                 float* __restrict__ alpha_src,
                                                 float* __restrict__ alpha_dst) {
    __shared__ __align__(16) f16 sAh[64 * LDA];        // 17408 B
    __shared__ __align__(16) f16 sAl[64 * LDA];        // 17408 B
    __shared__ __align__(16) f16 sWh[WCHUNKS * 8];     // 36864 B
    int t = threadIdx.x;
    int w = t >> 6, lane = t & 63;
    int row0 = blockIdx.x * 64;

    // stage W: flat copy of pre-padded image
    {
        const uint4* wsrc = (const uint4*)Wt;
        uint4* wdst = (uint4*)sWh;
#pragma unroll
        for (int it = 0; it < 9; ++it) {
            int chunk = it * 256 + t;
            wdst[chunk] = wsrc[chunk];
        }
    }
    // stage X, split fp32 -> (hi, lo) fp16
#pragma unroll
    for (int q = 0; q < 4; ++q) {
        int id = q * 256 + t;                 // 0..1023 = 64 rows * 16 chunks
        int r = id >> 4, c = id & 15;
        int grow = row0 + r;
        float4 a = make_float4(0.f, 0.f, 0.f, 0.f), b = a;
        if (grow < NN) {
            const float4* p = (const float4*)(X + (size_t)grow * DD + c * 8);
            a = p[0]; b = p[1];
        }
        float xs[8] = {a.x, a.y, a.z, a.w, b.x, b.y, b.z, b.w};
        union { f16 h[8]; uint4 u; } H, L;
#pragma unroll
        for (int i = 0; i < 8; ++i) {
            f16 hv = (f16)xs[i];
            H.h[i] = hv;
            L.h[i] = (f16)(xs[i] - (float)hv);
        }
        int off = r * LDA + c * 8;
        *(uint4*)(sAh + off) = H.u;
        *(uint4*)(sAl + off) = L.u;
    }
    __syncthreads();

    int cl = lane & 15, qw = lane >> 4;
    f32x4 acc[8] = {};
    int aoff = (w * 16 + cl) * LDA;
#pragma unroll
    for (int ks = 0; ks < 4; ++ks) {
        int koff = ks * 32 + qw * 8;
        f16x8 ah = *(const f16x8*)(sAh + aoff + koff);
        f16x8 al = *(const f16x8*)(sAl + aoff + koff);
        f16x8 bh[8];
#pragma unroll
        for (int nf = 0; nf < 8; ++nf)
            bh[nf] = *(const f16x8*)(sWh + (nf * 16 + cl) * LDA + koff);
#pragma unroll
        for (int nf = 0; nf < 8; ++nf)
            acc[nf] = __builtin_amdgcn_mfma_f32_16x16x32_f16(ah, bh[nf], acc[nf], 0, 0, 0);
#pragma unroll
        for (int nf = 0; nf < 8; ++nf)
            acc[nf] = __builtin_amdgcn_mfma_f32_16x16x32_f16(al, bh[nf], acc[nf], 0, 0, 0);
    }

    // C/D frag: lane holds col = cl (within 16-col frag), rows qw*4 + i
    int rbase = row0 + w * 16 + qw * 4;
    if (MODE == 0) {
        float bc[8];
#pragma unroll
        for (int nf = 0; nf < 8; ++nf) bc[nf] = bias[nf * 16 + cl];
#pragma unroll
        for (int i = 0; i < 4; ++i) {
            int row = rbase + i;
            if (row < NN) {
#pragma unroll
                for (int nf = 0; nf < 8; ++nf) {
                    float v = acc[nf][i] + bc[nf];
                    v = v > 0.f ? v : 0.01f * v;
                    Yf[(size_t)row * DD + nf * 16 + cl] = v;
                }
            }
        }
    } else {
        float as[8], ad[8];
#pragma unroll
        for (int nf = 0; nf < 8; ++nf) {
            as[nf] = av_src[nf * 16 + cl];
            ad[nf] = av_dst[nf * 16 + cl];
        }
        float pa[4] = {0.f, 0.f, 0.f, 0.f}, pb[4] = {0.f, 0.f, 0.f, 0.f};
#pragma unroll
        for (int nf = 0; nf < 8; ++nf) {
#pragma unroll
            for (int i = 0; i < 4; ++i) {
                float v = acc[nf][i];
                pa[i] += v * as[nf];
                pb[i] += v * ad[nf];
            }
        }
#pragma unroll
        for (int i = 0; i < 4; ++i) {
            int row = rbase + i;
            if (row < NN) {
#pragma unroll
                for (int nf = 0; nf < 8; ++nf)
                    Yh[(size_t)row * DD + nf * 16 + cl] = __float2half(acc[nf][i]);
            }
        }
#pragma unroll
        for (int i = 0; i < 4; ++i) {
#pragma unroll
            for (int off = 8; off >= 1; off >>= 1) {
                pa[i] += __shfl_xor(pa[i], off);
                pb[i] += __shfl_xor(pb[i], off);
            }
        }
        if (cl == 0) {
#pragma unroll
            for (int i = 0; i < 4; ++i) {
                int row = rbase + i;
                if (row < NN) {
                    alpha_src[row] = pa[i];
                    alpha_dst[row] = pb[i];
                }
            }
        }
    }
}

// ---------------- per-edge softmax weights (no max subtraction; |e| bounded) ----------------
__global__ __launch_bounds__(256) void edgew_k(const int* __restrict__ ssrc,
                                               const int* __restrict__ sdst,
                                               const float* __restrict__ alpha_src,
                                               const float* __restrict__ alpha_dst,
                                               float* __restrict__ wexp) {
    int j = blockIdx.x * 256 + threadIdx.x;
    if (j < EE) {
        float e = alpha_src[ssrc[j]] + alpha_dst[sdst[j]];
        e = e > 0.f ? e : 0.2f * e;
        wexp[j] = __expf(e);
    }
}

// ---------------- Per-dst aggregation + softmax-normalize + bias + LN + leaky ----------------
// one wave per dst node; lane c owns channels 2c, 2c+1
__global__ __launch_bounds__(256) void agg_k(const __half* __restrict__ tmp,
                                             const int* __restrict__ ssrc,
                                             const int* __restrict__ offsets,
                                             const float* __restrict__ wexp,
                                             const float* __restrict__ bias,
                                             const float* __restrict__ gamma,
                                             const float* __restrict__ beta,
                                             float* __restrict__ out) {
    int wid = (blockIdx.x * 256 + threadIdx.x) >> 6;
    int lane = threadIdx.x & 63;
    int beg = offsets[wid], end = offsets[wid + 1];

    float2 accA = make_float2(0.f, 0.f);
    float2 accB = make_float2(0.f, 0.f);
    float dsum = 0.f;
    const __half2* tmp2 = (const __half2*)tmp;
    for (int base = beg; base < end; base += 64) {
        int j = base + lane;
        float wv = 0.f; int s = 0;
        if (j < end) { wv = wexp[j]; s = ssrc[j]; }
        dsum += wv;
        int cnt = end - base; if (cnt > 64) cnt = 64;
        int jj = 0;
        for (; jj + 7 < cnt; jj += 8) {
            float w0 = __shfl(wv, jj + 0), w1 = __shfl(wv, jj + 1);
            float w2 = __shfl(wv, jj + 2), w3 = __shfl(wv, jj + 3);
            float w4 = __shfl(wv, jj + 4), w5 = __shfl(wv, jj + 5);
            float w6 = __shfl(wv, jj + 6), w7 = __shfl(wv, jj + 7);
            int s0 = __shfl(s, jj + 0), s1 = __shfl(s, jj + 1);
            int s2 = __shfl(s, jj + 2), s3 = __shfl(s, jj + 3);
            int s4 = __shfl(s, jj + 4), s5 = __shfl(s, jj + 5);
            int s6 = __shfl(s, jj + 6), s7 = __shfl(s, jj + 7);
            float2 h0 = __half22float2(tmp2[(size_t)s0 * 64 + lane]);
            float2 h1 = __half22float2(tmp2[(size_t)s1 * 64 + lane]);
            float2 h2 = __half22float2(tmp2[(size_t)s2 * 64 + lane]);
            float2 h3 = __half22float2(tmp2[(size_t)s3 * 64 + lane]);
            float2 h4 = __half22float2(tmp2[(size_t)s4 * 64 + lane]);
            float2 h5 = __half22float2(tmp2[(size_t)s5 * 64 + lane]);
            float2 h6 = __half22float2(tmp2[(size_t)s6 * 64 + lane]);
            float2 h7 = __half22float2(tmp2[(size_t)s7 * 64 + lane]);
            accA.x += w0 * h0.x; accA.y += w0 * h0.y;
            accB.x += w1 * h1.x; accB.y += w1 * h1.y;
            accA.x += w2 * h2.x; accA.y += w2 * h2.y;
            accB.x += w3 * h3.x; accB.y += w3 * h3.y;
            accA.x += w4 * h4.x; accA.y += w4 * h4.y;
            accB.x += w5 * h5.x; accB.y += w5 * h5.y;
            accA.x += w6 * h6.x; accA.y += w6 * h6.y;
            accB.x += w7 * h7.x; accB.y += w7 * h7.y;
        }
        for (; jj < cnt; jj++) {
            float w = __shfl(wv, jj);
            int ss = __shfl(s, jj);
            float2 hv = __half22float2(tmp2[(size_t)ss * 64 + lane]);
            accA.x += w * hv.x;
            accA.y += w * hv.y;
        }
    }
#pragma unroll
    for (int off = 32; off >= 1; off >>= 1) dsum += __shfl_xor(dsum, off);
    float inv = 1.0f / (dsum + 1e-16f);

    float ax = (accA.x + accB.x) * inv + bias[2 * lane];
    float ay = (accA.y + accB.y) * inv + bias[2 * lane + 1];

    float s1 = ax + ay;
#pragma unroll
    for (int off = 32; off >= 1; off >>= 1) s1 += __shfl_xor(s1, off);
    float mu = s1 * (1.0f / 128.0f);
    float dx = ax - mu, dy = ay - mu;
    float s2 = dx * dx + dy * dy;
#pragma unroll
    for (int off = 32; off >= 1; off >>= 1) s2 += __shfl_xor(s2, off);
    float rstd = rsqrtf(s2 * (1.0f / 128.0f) + 1e-5f);

    float yx = dx * rstd * gamma[2 * lane] + beta[2 * lane];
    float yy = dy * rstd * gamma[2 * lane + 1] + beta[2 * lane + 1];
    yx = yx > 0.f ? yx : 0.01f * yx;
    yy = yy > 0.f ? yy : 0.01f * yy;
    ((float2*)out)[(size_t)wid * 64 + lane] = make_float2(yx, yy);
}

extern "C" void kernel_launch(void* const* d_in, const int* in_sizes, int n_in,
                              void* d_out, int out_size, void* d_ws, size_t ws_size,
                              hipStream_t stream) {
    const float* x       = (const float*)d_in[0];
    const int*   ei      = (const int*)d_in[1];
    const float* W_in    = (const float*)d_in[2];
    const float* b_in    = (const float*)d_in[3];
    const float* Wl      = (const float*)d_in[4];
    const float* att_src = (const float*)d_in[5];
    const float* att_dst = (const float*)d_in[6];
    const float* bias_l  = (const float*)d_in[7];
    const float* gamma   = (const float*)d_in[8];
    const float* beta    = (const float*)d_in[9];
    float* out = (float*)d_out;

    char* ws = (char*)d_ws;
    __half* tmp      = (__half*)ws; ws += (size_t)NN * DD * 2;   // 25.6 MB
    float* alpha_src = (float*)ws;  ws += (size_t)NN * 4;
    float* alpha_dst = (float*)ws;  ws += (size_t)NN * 4;
    int*   offsets   = (int*)ws;    ws += (size_t)(NN + 4) * 4;
    int*   ssrc      = (int*)ws;    ws += (size_t)EE * 4;        // 6.4 MB
    int*   sdst      = (int*)ws;    ws += (size_t)EE * 4;        // 6.4 MB
    int2*  ebuf      = (int2*)ws;   ws += (size_t)EE * 8;        // 12.8 MB (dead after CSR build)
    int*   bcnt      = (int*)ws;    ws += (size_t)NBUCK * NBLKP * 4;
    int*   ebase     = (int*)ws;    ws += (size_t)NBUCK * NBLKP * 4;
    int*   btot      = (int*)ws;    ws += (size_t)(NBUCK + 4) * 4;
    int*   bstart    = (int*)ws;    ws += (size_t)(NBUCK + 4) * 4;
    f16*   Wt        = (f16*)ws;    ws += (size_t)5 * WCHUNKS * 16;  // 184 KB
    float* wexp = (float*)ebuf;     // aliases ebuf: written only after bucket_sort_k

    const int* esrc = ei;
    const int* edst = ei + EE;

    // bucketed CSR build (edges constant within a launch)
    part_hist_k<<<NBLKP, 256, 0, stream>>>(edst, bcnt);
    scanBB_k<<<NBUCK, 256, 0, stream>>>(bcnt, ebase, btot);
    scanBT_k<<<1, 256, 0, stream>>>(btot, bstart, offsets);
    part_k<<<NBLKP, 256, 0, stream>>>(esrc, edst, bstart, ebase, ebuf);
    bucket_sort_k<<<NBUCK, 512, 0, stream>>>(ebuf, bstart, offsets, ssrc, sdst);
    wprep_k<<<5, 256, 0, stream>>>(W_in, Wl, Wt);

    const int gg = (NN + 63) / 64;  // 1563

    // input projection: h0 = leaky(x @ W_in + b_in)
    gemm_k<0><<<gg, 256, 0, stream>>>(x, Wt, b_in, nullptr, nullptr, out, nullptr, nullptr, nullptr);

    for (int i = 0; i < 4; i++) {
        gemm_k<1><<<gg, 256, 0, stream>>>(out, Wt + (size_t)(i + 1) * (WCHUNKS * 8), nullptr,
                                          att_src + (size_t)i * DD, att_dst + (size_t)i * DD,
                                          nullptr, tmp, alpha_src, alpha_dst);
        edgew_k<<<EE / 256, 256, 0, stream>>>(ssrc, sdst, alpha_src, alpha_dst, wexp);
        agg_k<<<NN / 4, 256, 0, stream>>>(tmp, ssrc, offsets, wexp,
                                          bias_l + (size_t)i * DD, gamma + (size_t)i * DD,
                                          beta + (size_t)i * DD, out);
    }
}

// Round 2
// 605.608 us; speedup vs baseline: 1.2194x; 1.0045x over previous
//
#include <hip/hip_runtime.h>
#include <hip/hip_fp16.h>
#include <math.h>

#define NN 100000
#define EE 1600000
#define DD 128
#define NBUCK 196          // ceil(NN / 512) buckets of 512 dst nodes
#define NBLKP 196          // partition blocks, 8192 edges each (196*8192 >= EE)
#define EPB 8192           // edges per partition block

typedef _Float16 f16;
typedef f16 f16x8 __attribute__((ext_vector_type(8)));
typedef float f32x4 __attribute__((ext_vector_type(4)));

#define LDA 136            // padded LDS row stride in halves (272 B = 17*16)
#define WCHUNKS 2304       // 36864 B per W matrix image (128*136 halves + pad)

// ---------- bucketed CSR build ----------
__global__ __launch_bounds__(256) void part_hist_k(const int* __restrict__ dst, int* __restrict__ bcnt) {
    __shared__ int lc[NBUCK];
    int t = threadIdx.x, blk = blockIdx.x;
    if (t < NBUCK) lc[t] = 0;
    __syncthreads();
    int e0 = blk * EPB;
    for (int i = t; i < EPB; i += 256) {
        int e = e0 + i;
        if (e < EE) atomicAdd(&lc[dst[e] >> 9], 1);
    }
    __syncthreads();
    if (t < NBUCK) bcnt[t * NBLKP + blk] = lc[t];
}

__global__ __launch_bounds__(256) void scanBB_k(const int* __restrict__ bcnt, int* __restrict__ ebase,
                                                int* __restrict__ btot) {
    __shared__ int sh[256];
    int t = threadIdx.x, b = blockIdx.x;
    int c = (t < NBLKP) ? bcnt[b * NBLKP + t] : 0;
    sh[t] = c;
    __syncthreads();
    for (int off = 1; off < 256; off <<= 1) {
        int v = (t >= off) ? sh[t - off] : 0;
        __syncthreads();
        sh[t] += v;
        __syncthreads();
    }
    if (t < NBLKP) ebase[b * NBLKP + t] = sh[t] - c;  // exclusive
    if (t == 255) btot[b] = sh[255];
}

__global__ __launch_bounds__(256) void scanBT_k(const int* __restrict__ btot, int* __restrict__ bstart,
                                                int* __restrict__ offsets) {
    __shared__ int sh[256];
    int t = threadIdx.x;
    int c = (t < NBUCK) ? btot[t] : 0;
    sh[t] = c;
    __syncthreads();
    for (int off = 1; off < 256; off <<= 1) {
        int v = (t >= off) ? sh[t - off] : 0;
        __syncthreads();
        sh[t] += v;
        __syncthreads();
    }
    if (t < NBUCK) bstart[t] = sh[t] - c;
    if (t == 0) { bstart[NBUCK] = EE; offsets[NN] = EE; }
}

__global__ __launch_bounds__(256) void part_k(const int* __restrict__ src, const int* __restrict__ dst,
                                              const int* __restrict__ bstart, const int* __restrict__ ebase,
                                              int2* __restrict__ ebuf) {
    __shared__ int cur[NBUCK];
    int t = threadIdx.x, blk = blockIdx.x;
    if (t < NBUCK) cur[t] = bstart[t] + ebase[t * NBLKP + blk];
    __syncthreads();
    int e0 = blk * EPB;
    for (int i = t; i < EPB; i += 256) {
        int e = e0 + i;
        if (e < EE) {
            int s = src[e], d = dst[e];
            int p = atomicAdd(&cur[d >> 9], 1);
            ebuf[p] = make_int2(s, d);
        }
    }
}

__global__ __launch_bounds__(512) void bucket_sort_k(const int2* __restrict__ ebuf,
                                                     const int* __restrict__ bstart,
                                                     int* __restrict__ offsets,
                                                     int* __restrict__ ssrc,
                                                     int* __restrict__ sdst) {
    __shared__ int sh[512];
    __shared__ int cur[512];
    int t = threadIdx.x, b = blockIdx.x;
    int d0 = b << 9;
    int beg = bstart[b], end = bstart[b + 1];

    cur[t] = 0;
    __syncthreads();
    for (int e = beg + t; e < end; e += 512) atomicAdd(&cur[ebuf[e].y - d0], 1);
    __syncthreads();
    int c = cur[t];
    sh[t] = c;
    __syncthreads();
    for (int off = 1; off < 512; off <<= 1) {
        int v = (t >= off) ? sh[t - off] : 0;
        __syncthreads();
        sh[t] += v;
        __syncthreads();
    }
    int excl = sh[t] - c;
    if (d0 + t < NN) offsets[d0 + t] = beg + excl;
    cur[t] = beg + excl;
    __syncthreads();
    for (int e = beg + t; e < end; e += 512) {
        int2 ed = ebuf[e];
        int p = atomicAdd(&cur[ed.y - d0], 1);
        ssrc[p] = ed.x;
        sdst[p] = ed.y;
    }
}

// ---------------- W prep: transpose + fp16 round into LDS-image layout ----------------
__global__ __launch_bounds__(256) void wprep_k(const float* __restrict__ W_in,
                                               const float* __restrict__ Wl,
                                               f16* __restrict__ Wt) {
    int m = blockIdx.x;  // 0..4
    const float* src = (m == 0) ? W_in : (Wl + (size_t)(m - 1) * DD * DD);
    f16* dst = Wt + (size_t)m * (WCHUNKS * 8);
    for (int q = 0; q < 64; ++q) {
        int idx = q * 256 + threadIdx.x;   // 0..16383  (= k*128 + n)
        int k = idx >> 7, n = idx & 127;
        dst[n * LDA + k] = (f16)src[idx];
    }
}

// ---------------- GEMM: Y = X @ W via split-fp16 MFMA ----------------
template <int MODE>
__global__ __launch_bounds__(256, 2) void gemm_k(const float* __restrict__ X,
                                                 const f16* __restrict__ Wt,
                                                 const float* __restrict__ bias,
                                                 const float* __restrict__ av_src,
                                                 const float* __restrict__ av_dst,
                                                 float* __restrict__ Yf,
                                                 __half* __restrict__ Yh,
                                                 float* __restrict__ alpha_src,
                                                 float* __restrict__ alpha_dst) {
    __shared__ __align__(16) f16 sAh[64 * LDA];        // 17408 B
    __shared__ __align__(16) f16 sAl[64 * LDA];        // 17408 B
    __shared__ __align__(16) f16 sWh[WCHUNKS * 8];     // 36864 B
    int t = threadIdx.x;
    int w = t >> 6, lane = t & 63;
    int row0 = blockIdx.x * 64;

    // stage W: flat copy of pre-padded image
    {
        const uint4* wsrc = (const uint4*)Wt;
        uint4* wdst = (uint4*)sWh;
#pragma unroll
        for (int it = 0; it < 9; ++it) {
            int chunk = it * 256 + t;
            wdst[chunk] = wsrc[chunk];
        }
    }
    // stage X, split fp32 -> (hi, lo) fp16
#pragma unroll
    for (int q = 0; q < 4; ++q) {
        int id = q * 256 + t;                 // 0..1023 = 64 rows * 16 chunks
        int r = id >> 4, c = id & 15;
        int grow = row0 + r;
        float4 a = make_float4(0.f, 0.f, 0.f, 0.f), b = a;
        if (grow < NN) {
            const float4* p = (const float4*)(X + (size_t)grow * DD + c * 8);
            a = p[0]; b = p[1];
        }
        float xs[8] = {a.x, a.y, a.z, a.w, b.x, b.y, b.z, b.w};
        union { f16 h[8]; uint4 u; } H, L;
#pragma unroll
        for (int i = 0; i < 8; ++i) {
            f16 hv = (f16)xs[i];
            H.h[i] = hv;
            L.h[i] = (f16)(xs[i] - (float)hv);
        }
        int off = r * LDA + c * 8;
        *(uint4*)(sAh + off) = H.u;
        *(uint4*)(sAl + off) = L.u;
    }
    __syncthreads();

    int cl = lane & 15, qw = lane >> 4;
    f32x4 acc[8] = {};
    int aoff = (w * 16 + cl) * LDA;
#pragma unroll
    for (int ks = 0; ks < 4; ++ks) {
        int koff = ks * 32 + qw * 8;
        f16x8 ah = *(const f16x8*)(sAh + aoff + koff);
        f16x8 al = *(const f16x8*)(sAl + aoff + koff);
        f16x8 bh[8];
#pragma unroll
        for (int nf = 0; nf < 8; ++nf)
            bh[nf] = *(const f16x8*)(sWh + (nf * 16 + cl) * LDA + koff);
#pragma unroll
        for (int nf = 0; nf < 8; ++nf)
            acc[nf] = __builtin_amdgcn_mfma_f32_16x16x32_f16(ah, bh[nf], acc[nf], 0, 0, 0);
#pragma unroll
        for (int nf = 0; nf < 8; ++nf)
            acc[nf] = __builtin_amdgcn_mfma_f32_16x16x32_f16(al, bh[nf], acc[nf], 0, 0, 0);
    }

    int rbase = row0 + w * 16 + qw * 4;
    if (MODE == 0) {
        float bc[8];
#pragma unroll
        for (int nf = 0; nf < 8; ++nf) bc[nf] = bias[nf * 16 + cl];
#pragma unroll
        for (int i = 0; i < 4; ++i) {
            int row = rbase + i;
            if (row < NN) {
#pragma unroll
                for (int nf = 0; nf < 8; ++nf) {
                    float v = acc[nf][i] + bc[nf];
                    v = v > 0.f ? v : 0.01f * v;
                    Yf[(size_t)row * DD + nf * 16 + cl] = v;
                }
            }
        }
    } else {
        float as[8], ad[8];
#pragma unroll
        for (int nf = 0; nf < 8; ++nf) {
            as[nf] = av_src[nf * 16 + cl];
            ad[nf] = av_dst[nf * 16 + cl];
        }
        float pa[4] = {0.f, 0.f, 0.f, 0.f}, pb[4] = {0.f, 0.f, 0.f, 0.f};
#pragma unroll
        for (int nf = 0; nf < 8; ++nf) {
#pragma unroll
            for (int i = 0; i < 4; ++i) {
                float v = acc[nf][i];
                pa[i] += v * as[nf];
                pb[i] += v * ad[nf];
            }
        }
#pragma unroll
        for (int i = 0; i < 4; ++i) {
            int row = rbase + i;
            if (row < NN) {
#pragma unroll
                for (int nf = 0; nf < 8; ++nf)
                    Yh[(size_t)row * DD + nf * 16 + cl] = __float2half(acc[nf][i]);
            }
        }
#pragma unroll
        for (int i = 0; i < 4; ++i) {
#pragma unroll
            for (int off = 8; off >= 1; off >>= 1) {
                pa[i] += __shfl_xor(pa[i], off);
                pb[i] += __shfl_xor(pb[i], off);
            }
        }
        if (cl == 0) {
#pragma unroll
            for (int i = 0; i < 4; ++i) {
                int row = rbase + i;
                if (row < NN) {
                    alpha_src[row] = pa[i];
                    alpha_dst[row] = pb[i];
                }
            }
        }
    }
}

// ---------------- per-edge packed (src, exp-weight) records ----------------
__global__ __launch_bounds__(256) void edgew_k(const int* __restrict__ ssrc,
                                               const int* __restrict__ sdst,
                                               const float* __restrict__ alpha_src,
                                               const float* __restrict__ alpha_dst,
                                               int2* __restrict__ epk) {
    int j = blockIdx.x * 256 + threadIdx.x;
    if (j < EE) {
        int s = ssrc[j];
        float e = alpha_src[s] + alpha_dst[sdst[j]];
        e = e > 0.f ? e : 0.2f * e;
        epk[j] = make_int2(s, __float_as_int(__expf(e)));
    }
}

// ---------------- Per-dst aggregation + softmax-normalize + bias + LN + leaky ----------------
// one wave per dst node; lane c owns channels 2c, 2c+1.
// Edge metadata read via wave-uniform (scalar-pipe) loads -> no shuffles, no predication.
__global__ __launch_bounds__(256) void agg_k(const __half* __restrict__ tmp,
                                             const int2* __restrict__ epk,
                                             const int* __restrict__ offsets,
                                             const float* __restrict__ bias,
                                             const float* __restrict__ gamma,
                                             const float* __restrict__ beta,
                                             float* __restrict__ out) {
    int wid = (blockIdx.x * 256 + threadIdx.x) >> 6;
    wid = __builtin_amdgcn_readfirstlane(wid);
    int lane = threadIdx.x & 63;
    int beg = __builtin_amdgcn_readfirstlane(offsets[wid]);
    int end = __builtin_amdgcn_readfirstlane(offsets[wid + 1]);

    const __half2* tmp2 = (const __half2*)tmp;
    float accAx = 0.f, accAy = 0.f, accBx = 0.f, accBy = 0.f;
    float dsum = 0.f;

    int j = beg;
    // peel to even j so int4 (16 B) uniform loads are aligned
    if (j < end && (j & 1)) {
        int2 p = epk[j];
        float w = __int_as_float(p.y);
        __half2 h = tmp2[(size_t)p.x * 64 + lane];
        dsum += w;
        accAx = fmaf(w, __half2float(h.x), accAx);
        accAy = fmaf(w, __half2float(h.y), accAy);
        ++j;
    }
    for (; j + 8 <= end; j += 8) {
        int4 q0 = *(const int4*)(epk + j);
        int4 q1 = *(const int4*)(epk + j + 2);
        int4 q2 = *(const int4*)(epk + j + 4);
        int4 q3 = *(const int4*)(epk + j + 6);
        __half2 h0 = tmp2[(size_t)q0.x * 64 + lane];
        __half2 h1 = tmp2[(size_t)q0.z * 64 + lane];
        __half2 h2 = tmp2[(size_t)q1.x * 64 + lane];
        __half2 h3 = tmp2[(size_t)q1.z * 64 + lane];
        __half2 h4 = tmp2[(size_t)q2.x * 64 + lane];
        __half2 h5 = tmp2[(size_t)q2.z * 64 + lane];
        __half2 h6 = tmp2[(size_t)q3.x * 64 + lane];
        __half2 h7 = tmp2[(size_t)q3.z * 64 + lane];
        float w0 = __int_as_float(q0.y), w1 = __int_as_float(q0.w);
        float w2 = __int_as_float(q1.y), w3 = __int_as_float(q1.w);
        float w4 = __int_as_float(q2.y), w5 = __int_as_float(q2.w);
        float w6 = __int_as_float(q3.y), w7 = __int_as_float(q3.w);
        dsum += ((w0 + w1) + (w2 + w3)) + ((w4 + w5) + (w6 + w7));
        accAx = fmaf(w0, __half2float(h0.x), accAx);
        accAy = fmaf(w0, __half2float(h0.y), accAy);
        accBx = fmaf(w1, __half2float(h1.x), accBx);
        accBy = fmaf(w1, __half2float(h1.y), accBy);
        accAx = fmaf(w2, __half2float(h2.x), accAx);
        accAy = fmaf(w2, __half2float(h2.y), accAy);
        accBx = fmaf(w3, __half2float(h3.x), accBx);
        accBy = fmaf(w3, __half2float(h3.y), accBy);
        accAx = fmaf(w4, __half2float(h4.x), accAx);
        accAy = fmaf(w4, __half2float(h4.y), accAy);
        accBx = fmaf(w5, __half2float(h5.x), accBx);
        accBy = fmaf(w5, __half2float(h5.y), accBy);
        accAx = fmaf(w6, __half2float(h6.x), accAx);
        accAy = fmaf(w6, __half2float(h6.y), accAy);
        accBx = fmaf(w7, __half2float(h7.x), accBx);
        accBy = fmaf(w7, __half2float(h7.y), accBy);
    }
    for (; j < end; ++j) {
        int2 p = epk[j];
        float w = __int_as_float(p.y);
        __half2 h = tmp2[(size_t)p.x * 64 + lane];
        dsum += w;
        accAx = fmaf(w, __half2float(h.x), accAx);
        accAy = fmaf(w, __half2float(h.y), accAy);
    }

    // dsum is lane-uniform: no cross-lane reduction needed
    float inv = 1.0f / (dsum + 1e-16f);

    float ax = (accAx + accBx) * inv + bias[2 * lane];
    float ay = (accAy + accBy) * inv + bias[2 * lane + 1];

    float s1 = ax + ay;
#pragma unroll
    for (int off = 32; off >= 1; off >>= 1) s1 += __shfl_xor(s1, off);
    float mu = s1 * (1.0f / 128.0f);
    float dx = ax - mu, dy = ay - mu;
    float s2 = dx * dx + dy * dy;
#pragma unroll
    for (int off = 32; off >= 1; off >>= 1) s2 += __shfl_xor(s2, off);
    float rstd = rsqrtf(s2 * (1.0f / 128.0f) + 1e-5f);

    float yx = dx * rstd * gamma[2 * lane] + beta[2 * lane];
    float yy = dy * rstd * gamma[2 * lane + 1] + beta[2 * lane + 1];
    yx = yx > 0.f ? yx : 0.01f * yx;
    yy = yy > 0.f ? yy : 0.01f * yy;
    ((float2*)out)[(size_t)wid * 64 + lane] = make_float2(yx, yy);
}

extern "C" void kernel_launch(void* const* d_in, const int* in_sizes, int n_in,
                              void* d_out, int out_size, void* d_ws, size_t ws_size,
                              hipStream_t stream) {
    const float* x       = (const float*)d_in[0];
    const int*   ei      = (const int*)d_in[1];
    const float* W_in    = (const float*)d_in[2];
    const float* b_in    = (const float*)d_in[3];
    const float* Wl      = (const float*)d_in[4];
    const float* att_src = (const float*)d_in[5];
    const float* att_dst = (const float*)d_in[6];
    const float* bias_l  = (const float*)d_in[7];
    const float* gamma   = (const float*)d_in[8];
    const float* beta    = (const float*)d_in[9];
    float* out = (float*)d_out;

    char* ws = (char*)d_ws;
    __half* tmp      = (__half*)ws; ws += (size_t)NN * DD * 2;   // 25.6 MB
    float* alpha_src = (float*)ws;  ws += (size_t)NN * 4;
    float* alpha_dst = (float*)ws;  ws += (size_t)NN * 4;
    int*   offsets   = (int*)ws;    ws += (size_t)(NN + 4) * 4;
    int*   ssrc      = (int*)ws;    ws += (size_t)EE * 4;        // 6.4 MB
    int*   sdst      = (int*)ws;    ws += (size_t)EE * 4;        // 6.4 MB
    int2*  ebuf      = (int2*)ws;   ws += (size_t)EE * 8;        // 12.8 MB (dead after CSR build)
    int*   bcnt      = (int*)ws;    ws += (size_t)NBUCK * NBLKP * 4;
    int*   ebase     = (int*)ws;    ws += (size_t)NBUCK * NBLKP * 4;
    int*   btot      = (int*)ws;    ws += (size_t)(NBUCK + 4) * 4;
    int*   bstart    = (int*)ws;    ws += (size_t)(NBUCK + 4) * 4;
    f16*   Wt        = (f16*)ws;    ws += (size_t)5 * WCHUNKS * 16;  // 184 KB
    int2* epk = ebuf;               // aliases ebuf: written only after bucket_sort_k

    const int* esrc = ei;
    const int* edst = ei + EE;

    // bucketed CSR build (edges constant within a launch)
    part_hist_k<<<NBLKP, 256, 0, stream>>>(edst, bcnt);
    scanBB_k<<<NBUCK, 256, 0, stream>>>(bcnt, ebase, btot);
    scanBT_k<<<1, 256, 0, stream>>>(btot, bstart, offsets);
    part_k<<<NBLKP, 256, 0, stream>>>(esrc, edst, bstart, ebase, ebuf);
    bucket_sort_k<<<NBUCK, 512, 0, stream>>>(ebuf, bstart, offsets, ssrc, sdst);
    wprep_k<<<5, 256, 0, stream>>>(W_in, Wl, Wt);

    const int gg = (NN + 63) / 64;  // 1563

    // input projection: h0 = leaky(x @ W_in + b_in)
    gemm_k<0><<<gg, 256, 0, stream>>>(x, Wt, b_in, nullptr, nullptr, out, nullptr, nullptr, nullptr);

    for (int i = 0; i < 4; i++) {
        gemm_k<1><<<gg, 256, 0, stream>>>(out, Wt + (size_t)(i + 1) * (WCHUNKS * 8), nullptr,
                                          att_src + (size_t)i * DD, att_dst + (size_t)i * DD,
                                          nullptr, tmp, alpha_src, alpha_dst);
        edgew_k<<<EE / 256, 256, 0, stream>>>(ssrc, sdst, alpha_src, alpha_dst, epk);
        agg_k<<<NN / 4, 256, 0, stream>>>(tmp, epk, offsets,
                                          bias_l + (size_t)i * DD, gamma + (size_t)i * DD,
                                          beta + (size_t)i * DD, out);
    }
}

// Round 4
// 580.432 us; speedup vs baseline: 1.2723x; 1.0434x over previous
//
#include <hip/hip_runtime.h>
#include <hip/hip_fp16.h>
#include <math.h>

#define NN 100000
#define EE 1600000
#define DD 128
#define NBUCK 196          // ceil(NN / 512) buckets of 512 dst nodes
#define NBLKP 196          // partition blocks, 8192 edges each (196*8192 >= EE)
#define EPB 8192           // edges per partition block

typedef _Float16 f16;
typedef f16 f16x8 __attribute__((ext_vector_type(8)));
typedef float f32x4 __attribute__((ext_vector_type(4)));

#define LDA 136            // padded LDS row stride in halves (272 B = 17*16)
#define WCHUNKS 2304       // 36864 B per W matrix image (128*136 halves + pad)

// ---------- bucketed CSR build ----------
__global__ __launch_bounds__(256) void part_hist_k(const int* __restrict__ dst, int* __restrict__ bcnt) {
    __shared__ int lc[NBUCK];
    int t = threadIdx.x, blk = blockIdx.x;
    if (t < NBUCK) lc[t] = 0;
    __syncthreads();
    int e0 = blk * EPB;
    for (int i = t; i < EPB; i += 256) {
        int e = e0 + i;
        if (e < EE) atomicAdd(&lc[dst[e] >> 9], 1);
    }
    __syncthreads();
    if (t < NBUCK) bcnt[t * NBLKP + blk] = lc[t];
}

__global__ __launch_bounds__(256) void scanBB_k(const int* __restrict__ bcnt, int* __restrict__ ebase,
                                                int* __restrict__ btot) {
    __shared__ int sh[256];
    int t = threadIdx.x, b = blockIdx.x;
    int c = (t < NBLKP) ? bcnt[b * NBLKP + t] : 0;
    sh[t] = c;
    __syncthreads();
    for (int off = 1; off < 256; off <<= 1) {
        int v = (t >= off) ? sh[t - off] : 0;
        __syncthreads();
        sh[t] += v;
        __syncthreads();
    }
    if (t < NBLKP) ebase[b * NBLKP + t] = sh[t] - c;  // exclusive
    if (t == 255) btot[b] = sh[255];
}

__global__ __launch_bounds__(256) void scanBT_k(const int* __restrict__ btot, int* __restrict__ bstart,
                                                int* __restrict__ offsets) {
    __shared__ int sh[256];
    int t = threadIdx.x;
    int c = (t < NBUCK) ? btot[t] : 0;
    sh[t] = c;
    __syncthreads();
    for (int off = 1; off < 256; off <<= 1) {
        int v = (t >= off) ? sh[t - off] : 0;
        __syncthreads();
        sh[t] += v;
        __syncthreads();
    }
    if (t < NBUCK) bstart[t] = sh[t] - c;
    if (t == 0) { bstart[NBUCK] = EE; offsets[NN] = EE; }
}

__global__ __launch_bounds__(256) void part_k(const int* __restrict__ src, const int* __restrict__ dst,
                                              const int* __restrict__ bstart, const int* __restrict__ ebase,
                                              int2* __restrict__ ebuf) {
    __shared__ int cur[NBUCK];
    int t = threadIdx.x, blk = blockIdx.x;
    if (t < NBUCK) cur[t] = bstart[t] + ebase[t * NBLKP + blk];
    __syncthreads();
    int e0 = blk * EPB;
    for (int i = t; i < EPB; i += 256) {
        int e = e0 + i;
        if (e < EE) {
            int s = src[e], d = dst[e];
            int p = atomicAdd(&cur[d >> 9], 1);
            ebuf[p] = make_int2(s, d);
        }
    }
}

__global__ __launch_bounds__(512) void bucket_sort_k(const int2* __restrict__ ebuf,
                                                     const int* __restrict__ bstart,
                                                     int* __restrict__ offsets,
                                                     int* __restrict__ ssrc,
                                                     int* __restrict__ sdst) {
    __shared__ int sh[512];
    __shared__ int cur[512];
    int t = threadIdx.x, b = blockIdx.x;
    int d0 = b << 9;
    int beg = bstart[b], end = bstart[b + 1];

    cur[t] = 0;
    __syncthreads();
    for (int e = beg + t; e < end; e += 512) atomicAdd(&cur[ebuf[e].y - d0], 1);
    __syncthreads();
    int c = cur[t];
    sh[t] = c;
    __syncthreads();
    for (int off = 1; off < 512; off <<= 1) {
        int v = (t >= off) ? sh[t - off] : 0;
        __syncthreads();
        sh[t] += v;
        __syncthreads();
    }
    int excl = sh[t] - c;
    if (d0 + t < NN) offsets[d0 + t] = beg + excl;
    cur[t] = beg + excl;
    __syncthreads();
    for (int e = beg + t; e < end; e += 512) {
        int2 ed = ebuf[e];
        int p = atomicAdd(&cur[ed.y - d0], 1);
        ssrc[p] = ed.x;
        sdst[p] = ed.y;
    }
}

// ---------------- W prep: transpose + fp16 round into LDS-image layout ----------------
__global__ __launch_bounds__(256) void wprep_k(const float* __restrict__ W_in,
                                               const float* __restrict__ Wl,
                                               f16* __restrict__ Wt) {
    int m = blockIdx.x;  // 0..4
    const float* src = (m == 0) ? W_in : (Wl + (size_t)(m - 1) * DD * DD);
    f16* dst = Wt + (size_t)m * (WCHUNKS * 8);
    for (int q = 0; q < 64; ++q) {
        int idx = q * 256 + threadIdx.x;   // 0..16383  (= k*128 + n)
        int k = idx >> 7, n = idx & 127;
        dst[n * LDA + k] = (f16)src[idx];
    }
}

// ---------------- GEMM: Y = X @ W via fp16 MFMA, BM=128 tile ----------------
// 256 threads = 4 waves, each wave 32 rows x 128 cols.
// F32IN=1: X fp32 (rounded to fp16 at stage). F32IN=0: X already fp16.
// MODE 0: Yh = fp16(leaky(X@W + bias, 0.01)). MODE 1: Yh = fp16(X@W), alpha dots (fp32 acc).
template <int MODE, int F32IN>
__global__ __launch_bounds__(256, 2) void gemm_k(const void* __restrict__ Xv,
                                                 const f16* __restrict__ Wt,
                                                 const float* __restrict__ bias,
                                                 const float* __restrict__ av_src,
                                                 const float* __restrict__ av_dst,
                                                 __half* __restrict__ Yh,
                                                 float* __restrict__ alpha_src,
                                                 float* __restrict__ alpha_dst) {
    __shared__ __align__(16) f16 sA[128 * LDA];        // 34816 B
    __shared__ __align__(16) f16 sW[WCHUNKS * 8];      // 36864 B
    int t = threadIdx.x;
    int w = t >> 6, lane = t & 63;
    int row0 = blockIdx.x * 128;

    // stage W: flat copy of pre-padded image
    {
        const uint4* wsrc = (const uint4*)Wt;
        uint4* wdst = (uint4*)sW;
#pragma unroll
        for (int it = 0; it < 9; ++it) wdst[it * 256 + t] = wsrc[it * 256 + t];
    }
    // stage X: 128 rows x 16 chunks of 8 halves (2048 ids)
    if (F32IN) {
        const float* X = (const float*)Xv;
#pragma unroll
        for (int q = 0; q < 8; ++q) {
            int id = q * 256 + t;
            int r = id >> 4, c = id & 15;
            int grow = row0 + r;
            float4 a = make_float4(0.f, 0.f, 0.f, 0.f), b = a;
            if (grow < NN) {
                const float4* p = (const float4*)(X + (size_t)grow * DD + c * 8);
                a = p[0]; b = p[1];
            }
            union { f16 h[8]; uint4 u; } H;
            H.h[0] = (f16)a.x; H.h[1] = (f16)a.y; H.h[2] = (f16)a.z; H.h[3] = (f16)a.w;
            H.h[4] = (f16)b.x; H.h[5] = (f16)b.y; H.h[6] = (f16)b.z; H.h[7] = (f16)b.w;
            *(uint4*)(sA + r * LDA + c * 8) = H.u;
        }
    } else {
        const __half* X = (const __half*)Xv;
#pragma unroll
        for (int q = 0; q < 8; ++q) {
            int id = q * 256 + t;
            int r = id >> 4, c = id & 15;
            int grow = row0 + r;
            uint4 v = make_uint4(0, 0, 0, 0);
            if (grow < NN) v = ((const uint4*)(X + (size_t)grow * DD))[c];
            *(uint4*)(sA + r * LDA + c * 8) = v;
        }
    }
    __syncthreads();

    int cl = lane & 15, qw = lane >> 4;
    f32x4 acc[2][8] = {};
#pragma unroll
    for (int ks = 0; ks < 4; ++ks) {
        int koff = ks * 32 + qw * 8;
        f16x8 bh[8];
#pragma unroll
        for (int nf = 0; nf < 8; ++nf)
            bh[nf] = *(const f16x8*)(sW + (nf * 16 + cl) * LDA + koff);
#pragma unroll
        for (int rf = 0; rf < 2; ++rf) {
            f16x8 ah = *(const f16x8*)(sA + (w * 32 + rf * 16 + cl) * LDA + koff);
#pragma unroll
            for (int nf = 0; nf < 8; ++nf)
                acc[rf][nf] = __builtin_amdgcn_mfma_f32_16x16x32_f16(ah, bh[nf], acc[rf][nf], 0, 0, 0);
        }
    }

    if (MODE == 0) {
        float bc[8];
#pragma unroll
        for (int nf = 0; nf < 8; ++nf) bc[nf] = bias[nf * 16 + cl];
#pragma unroll
        for (int rf = 0; rf < 2; ++rf) {
            int rbase = row0 + w * 32 + rf * 16 + qw * 4;
#pragma unroll
            for (int i = 0; i < 4; ++i) {
                int row = rbase + i;
                if (row < NN) {
#pragma unroll
                    for (int nf = 0; nf < 8; ++nf) {
                        float v = acc[rf][nf][i] + bc[nf];
                        v = v > 0.f ? v : 0.01f * v;
                        Yh[(size_t)row * DD + nf * 16 + cl] = __float2half(v);
                    }
                }
            }
        }
    } else {
        float as[8], ad[8];
#pragma unroll
        for (int nf = 0; nf < 8; ++nf) {
            as[nf] = av_src[nf * 16 + cl];
            ad[nf] = av_dst[nf * 16 + cl];
        }
#pragma unroll
        for (int rf = 0; rf < 2; ++rf) {
            int rbase = row0 + w * 32 + rf * 16 + qw * 4;
            float pa[4] = {0.f, 0.f, 0.f, 0.f}, pb[4] = {0.f, 0.f, 0.f, 0.f};
#pragma unroll
            for (int nf = 0; nf < 8; ++nf) {
#pragma unroll
                for (int i = 0; i < 4; ++i) {
                    float v = acc[rf][nf][i];
                    pa[i] += v * as[nf];
                    pb[i] += v * ad[nf];
                }
            }
#pragma unroll
            for (int i = 0; i < 4; ++i) {
                int row = rbase + i;
                if (row < NN) {
#pragma unroll
                    for (int nf = 0; nf < 8; ++nf)
                        Yh[(size_t)row * DD + nf * 16 + cl] = __float2half(acc[rf][nf][i]);
                }
            }
#pragma unroll
            for (int i = 0; i < 4; ++i) {
#pragma unroll
                for (int off = 8; off >= 1; off >>= 1) {
                    pa[i] += __shfl_xor(pa[i], off);
                    pb[i] += __shfl_xor(pb[i], off);
                }
            }
            if (cl == 0) {
#pragma unroll
                for (int i = 0; i < 4; ++i) {
                    int row = rbase + i;
                    if (row < NN) {
                        alpha_src[row] = pa[i];
                        alpha_dst[row] = pb[i];
                    }
                }
            }
        }
    }
}

// ---------------- per-edge packed (src, exp-weight) records + 16-record pad ----------------
__global__ __launch_bounds__(256) void edgew_k(const int* __restrict__ ssrc,
                                               const int* __restrict__ sdst,
                                               const float* __restrict__ alpha_src,
                                               const float* __restrict__ alpha_dst,
                                               int2* __restrict__ epk) {
    int j = blockIdx.x * 256 + threadIdx.x;
    if (j < EE) {
        int s = ssrc[j];
        float e = alpha_src[s] + alpha_dst[sdst[j]];
        e = e > 0.f ? e : 0.2f * e;
        epk[j] = make_int2(s, __float_as_int(__expf(e)));
    } else if (j < EE + 16) {
        epk[j] = make_int2(0, 0);   // pad: row 0, weight 0 (masked anyway)
    }
}

// ---------------- Per-dst aggregation + softmax-normalize + bias + LN + leaky ----------------
// one wave per dst node; lane c owns channels 2c, 2c+1.
// Edge metadata via wave-uniform scalar loads; fixed 16-wide masked window (scalar s_cselect masks)
// so the average node (deg~16) completes in one iteration with all gathers in flight.
template <int HOUT>
__global__ __launch_bounds__(256) void agg_k(const __half* __restrict__ tmp,
                                             const int2* __restrict__ epk,
                                             const int* __restrict__ offsets,
                                             const float* __restrict__ bias,
                                             const float* __restrict__ gamma,
                                             const float* __restrict__ beta,
                                             void* __restrict__ outv) {
    int wid = (blockIdx.x * 256 + threadIdx.x) >> 6;
    wid = __builtin_amdgcn_readfirstlane(wid);
    int lane = threadIdx.x & 63;
    int beg = __builtin_amdgcn_readfirstlane(offsets[wid]);
    int end = __builtin_amdgcn_readfirstlane(offsets[wid + 1]);

    const __half2* tmp2 = (const __half2*)tmp;
    float ax0 = 0.f, ay0 = 0.f, ax1 = 0.f, ay1 = 0.f, dsum = 0.f;

    for (int j = (beg & ~1); j < end; j += 16) {
        int4 q[8];
#pragma unroll
        for (int k = 0; k < 8; ++k) q[k] = *(const int4*)(epk + j + 2 * k);
        __half2 h[16];
#pragma unroll
        for (int k = 0; k < 8; ++k) {
            h[2 * k]     = tmp2[(size_t)q[k].x * 64 + lane];
            h[2 * k + 1] = tmp2[(size_t)q[k].z * 64 + lane];
        }
#pragma unroll
        for (int k = 0; k < 8; ++k) {
            int e0 = j + 2 * k, e1 = e0 + 1;
            bool v0 = (k == 0) ? (e0 >= beg && e0 < end) : (e0 < end);
            bool v1 = (e1 < end);
            float w0 = v0 ? __int_as_float(q[k].y) : 0.f;
            float w1 = v1 ? __int_as_float(q[k].w) : 0.f;
            dsum += w0 + w1;
            ax0 = fmaf(w0, __half2float(h[2 * k].x), ax0);
            ay0 = fmaf(w0, __half2float(h[2 * k].y), ay0);
            ax1 = fmaf(w1, __half2float(h[2 * k + 1].x), ax1);
            ay1 = fmaf(w1, __half2float(h[2 * k + 1].y), ay1);
        }
    }

    // dsum is lane-uniform: no cross-lane reduction needed
    float inv = 1.0f / (dsum + 1e-16f);

    float ax = (ax0 + ax1) * inv + bias[2 * lane];
    float ay = (ay0 + ay1) * inv + bias[2 * lane + 1];

    float s1 = ax + ay;
#pragma unroll
    for (int off = 32; off >= 1; off >>= 1) s1 += __shfl_xor(s1, off);
    float mu = s1 * (1.0f / 128.0f);
    float dx = ax - mu, dy = ay - mu;
    float s2 = dx * dx + dy * dy;
#pragma unroll
    for (int off = 32; off >= 1; off >>= 1) s2 += __shfl_xor(s2, off);
    float rstd = rsqrtf(s2 * (1.0f / 128.0f) + 1e-5f);

    float yx = dx * rstd * gamma[2 * lane] + beta[2 * lane];
    float yy = dy * rstd * gamma[2 * lane + 1] + beta[2 * lane + 1];
    yx = yx > 0.f ? yx : 0.01f * yx;
    yy = yy > 0.f ? yy : 0.01f * yy;
    if (HOUT) {
        ((__half2*)outv)[(size_t)wid * 64 + lane] = __floats2half2_rn(yx, yy);
    } else {
        ((float2*)outv)[(size_t)wid * 64 + lane] = make_float2(yx, yy);
    }
}

extern "C" void kernel_launch(void* const* d_in, const int* in_sizes, int n_in,
                              void* d_out, int out_size, void* d_ws, size_t ws_size,
                              hipStream_t stream) {
    const float* x       = (const float*)d_in[0];
    const int*   ei      = (const int*)d_in[1];
    const float* W_in    = (const float*)d_in[2];
    const float* b_in    = (const float*)d_in[3];
    const float* Wl      = (const float*)d_in[4];
    const float* att_src = (const float*)d_in[5];
    const float* att_dst = (const float*)d_in[6];
    const float* bias_l  = (const float*)d_in[7];
    const float* gamma   = (const float*)d_in[8];
    const float* beta    = (const float*)d_in[9];
    float* out = (float*)d_out;

    char* ws = (char*)d_ws;
    __half* tmp      = (__half*)ws; ws += (size_t)NN * DD * 2;   // 25.6 MB
    float* alpha_src = (float*)ws;  ws += (size_t)NN * 4;
    float* alpha_dst = (float*)ws;  ws += (size_t)NN * 4;
    int*   offsets   = (int*)ws;    ws += (size_t)(NN + 4) * 4;
    int*   ssrc      = (int*)ws;    ws += (size_t)EE * 4;        // 6.4 MB
    int*   sdst      = (int*)ws;    ws += (size_t)EE * 4;        // 6.4 MB
    int2*  ebuf      = (int2*)ws;   ws += (size_t)(EE + 16) * 8; // 12.8 MB (dead after CSR build)
    int*   bcnt      = (int*)ws;    ws += (size_t)NBUCK * NBLKP * 4;
    int*   ebase     = (int*)ws;    ws += (size_t)NBUCK * NBLKP * 4;
    int*   btot      = (int*)ws;    ws += (size_t)(NBUCK + 4) * 4;
    int*   bstart    = (int*)ws;    ws += (size_t)(NBUCK + 4) * 4;
    f16*   Wt        = (f16*)ws;    ws += (size_t)5 * WCHUNKS * 16;  // 184 KB
    int2* epk = ebuf;               // aliases ebuf: written only after bucket_sort_k

    // fp16 hidden-state buffer lives in the (not-yet-needed) d_out allocation:
    // layers 0..2 store h as fp16 in the first 25.6 MB; the final agg_k fully
    // overwrites d_out with fp32 output.
    __half* hbuf = (__half*)d_out;

    const int* esrc = ei;
    const int* edst = ei + EE;

    // bucketed CSR build (edges constant within a launch)
    part_hist_k<<<NBLKP, 256, 0, stream>>>(edst, bcnt);
    scanBB_k<<<NBUCK, 256, 0, stream>>>(bcnt, ebase, btot);
    scanBT_k<<<1, 256, 0, stream>>>(btot, bstart, offsets);
    part_k<<<NBLKP, 256, 0, stream>>>(esrc, edst, bstart, ebase, ebuf);
    bucket_sort_k<<<NBUCK, 512, 0, stream>>>(ebuf, bstart, offsets, ssrc, sdst);
    wprep_k<<<5, 256, 0, stream>>>(W_in, Wl, Wt);

    const int gg = (NN + 127) / 128;          // 782
    const int eg = (EE + 16 + 255) / 256;     // 6251 (covers pad records)

    // input projection: h0 = fp16(leaky(x @ W_in + b_in))
    gemm_k<0, 1><<<gg, 256, 0, stream>>>(x, Wt, b_in, nullptr, nullptr, hbuf, nullptr, nullptr);

    for (int i = 0; i < 4; i++) {
        gemm_k<1, 0><<<gg, 256, 0, stream>>>(hbuf, Wt + (size_t)(i + 1) * (WCHUNKS * 8), nullptr,
                                             att_src + (size_t)i * DD, att_dst + (size_t)i * DD,
                                             tmp, alpha_src, alpha_dst);
        edgew_k<<<eg, 256, 0, stream>>>(ssrc, sdst, alpha_src, alpha_dst, epk);
        if (i < 3) {
            agg_k<1><<<NN / 4, 256, 0, stream>>>(tmp, epk, offsets,
                                                 bias_l + (size_t)i * DD, gamma + (size_t)i * DD,
                                                 beta + (size_t)i * DD, (void*)hbuf);
        } else {
            agg_k<0><<<NN / 4, 256, 0, stream>>>(tmp, epk, offsets,
                                                 bias_l + (size_t)i * DD, gamma + (size_t)i * DD,
                                                 beta + (size_t)i * DD, (void*)out);
        }
    }
}

// Round 5
// 576.699 us; speedup vs baseline: 1.2806x; 1.0065x over previous
//
#include <hip/hip_runtime.h>
#include <hip/hip_fp16.h>
#include <math.h>

#define NN 100000
#define EE 1600000
#define DD 128
#define NBUCK 196          // ceil(NN / 512) buckets of 512 dst nodes
#define NBLKP 196          // partition blocks, 8192 edges each (196*8192 >= EE)
#define EPB 8192           // edges per partition block

typedef _Float16 f16;
typedef f16 f16x8 __attribute__((ext_vector_type(8)));
typedef float f32x4 __attribute__((ext_vector_type(4)));

#define LDA 136            // padded LDS row stride in halves (272 B = 17*16)
#define WCHUNKS 2304       // 36864 B per W matrix image (128*136 halves + pad)

// ---------- bucketed CSR build ----------
__global__ __launch_bounds__(256) void part_hist_k(const int* __restrict__ dst, int* __restrict__ bcnt) {
    __shared__ int lc[NBUCK];
    int t = threadIdx.x, blk = blockIdx.x;
    if (t < NBUCK) lc[t] = 0;
    __syncthreads();
    int e0 = blk * EPB;
    for (int i = t; i < EPB; i += 256) {
        int e = e0 + i;
        if (e < EE) atomicAdd(&lc[dst[e] >> 9], 1);
    }
    __syncthreads();
    if (t < NBUCK) bcnt[t * NBLKP + blk] = lc[t];
}

__global__ __launch_bounds__(256) void scanBB_k(const int* __restrict__ bcnt, int* __restrict__ ebase,
                                                int* __restrict__ btot) {
    __shared__ int sh[256];
    int t = threadIdx.x, b = blockIdx.x;
    int c = (t < NBLKP) ? bcnt[b * NBLKP + t] : 0;
    sh[t] = c;
    __syncthreads();
    for (int off = 1; off < 256; off <<= 1) {
        int v = (t >= off) ? sh[t - off] : 0;
        __syncthreads();
        sh[t] += v;
        __syncthreads();
    }
    if (t < NBLKP) ebase[b * NBLKP + t] = sh[t] - c;  // exclusive
    if (t == 255) btot[b] = sh[255];
}

__global__ __launch_bounds__(256) void scanBT_k(const int* __restrict__ btot, int* __restrict__ bstart,
                                                int* __restrict__ offsets) {
    __shared__ int sh[256];
    int t = threadIdx.x;
    int c = (t < NBUCK) ? btot[t] : 0;
    sh[t] = c;
    __syncthreads();
    for (int off = 1; off < 256; off <<= 1) {
        int v = (t >= off) ? sh[t - off] : 0;
        __syncthreads();
        sh[t] += v;
        __syncthreads();
    }
    if (t < NBUCK) bstart[t] = sh[t] - c;
    if (t == 0) { bstart[NBUCK] = EE; offsets[NN] = EE; }
}

__global__ __launch_bounds__(256) void part_k(const int* __restrict__ src, const int* __restrict__ dst,
                                              const int* __restrict__ bstart, const int* __restrict__ ebase,
                                              int2* __restrict__ ebuf) {
    __shared__ int cur[NBUCK];
    int t = threadIdx.x, blk = blockIdx.x;
    if (t < NBUCK) cur[t] = bstart[t] + ebase[t * NBLKP + blk];
    __syncthreads();
    int e0 = blk * EPB;
    for (int i = t; i < EPB; i += 256) {
        int e = e0 + i;
        if (e < EE) {
            int s = src[e], d = dst[e];
            int p = atomicAdd(&cur[d >> 9], 1);
            ebuf[p] = make_int2(s, d);
        }
    }
}

__global__ __launch_bounds__(512) void bucket_sort_k(const int2* __restrict__ ebuf,
                                                     const int* __restrict__ bstart,
                                                     int* __restrict__ offsets,
                                                     int* __restrict__ ssrc,
                                                     int* __restrict__ sdst) {
    __shared__ int sh[512];
    __shared__ int cur[512];
    int t = threadIdx.x, b = blockIdx.x;
    int d0 = b << 9;
    int beg = bstart[b], end = bstart[b + 1];

    cur[t] = 0;
    __syncthreads();
    for (int e = beg + t; e < end; e += 512) atomicAdd(&cur[ebuf[e].y - d0], 1);
    __syncthreads();
    int c = cur[t];
    sh[t] = c;
    __syncthreads();
    for (int off = 1; off < 512; off <<= 1) {
        int v = (t >= off) ? sh[t - off] : 0;
        __syncthreads();
        sh[t] += v;
        __syncthreads();
    }
    int excl = sh[t] - c;
    if (d0 + t < NN) offsets[d0 + t] = beg + excl;
    cur[t] = beg + excl;
    __syncthreads();
    for (int e = beg + t; e < end; e += 512) {
        int2 ed = ebuf[e];
        int p = atomicAdd(&cur[ed.y - d0], 1);
        ssrc[p] = ed.x;
        sdst[p] = ed.y;
    }
}

// ---------------- W prep: transpose + fp16 round into LDS-image layout ----------------
__global__ __launch_bounds__(256) void wprep_k(const float* __restrict__ W_in,
                                               const float* __restrict__ Wl,
                                               f16* __restrict__ Wt) {
    int m = blockIdx.x;  // 0..4
    const float* src = (m == 0) ? W_in : (Wl + (size_t)(m - 1) * DD * DD);
    f16* dst = Wt + (size_t)m * (WCHUNKS * 8);
    for (int q = 0; q < 64; ++q) {
        int idx = q * 256 + threadIdx.x;   // 0..16383  (= k*128 + n)
        int k = idx >> 7, n = idx & 127;
        dst[n * LDA + k] = (f16)src[idx];
    }
}

// ---------------- GEMM: Y = X @ W via fp16 MFMA ----------------
// BM=128 per block, 256 threads = 4 waves, each wave 32 rows x 128 cols.
// A fragments loaded DIRECTLY global->VGPR (fragment layout == 16 contiguous bytes
// of a row-major X row); only W goes through LDS (36 KB).
// F32IN=1: X fp32 (rounded to fp16 in regs). F32IN=0: X already fp16.
// MODE 0: Yh = fp16(leaky(X@W + bias, 0.01)). MODE 1: Yh = fp16(X@W), alpha dots.
template <int MODE, int F32IN>
__global__ __launch_bounds__(256, 3) void gemm_k(const void* __restrict__ Xv,
                                                 const f16* __restrict__ Wt,
                                                 const float* __restrict__ bias,
                                                 const float* __restrict__ av_src,
                                                 const float* __restrict__ av_dst,
                                                 __half* __restrict__ Yh,
                                                 float* __restrict__ alpha_src,
                                                 float* __restrict__ alpha_dst) {
    __shared__ __align__(16) f16 sW[WCHUNKS * 8];      // 36864 B
    int t = threadIdx.x;
    int w = t >> 6, lane = t & 63;
    int cl = lane & 15, qw = lane >> 4;
    int row0 = blockIdx.x * 128;

    // A fragments: row = row0 + w*32 + rf*16 + cl, k-span = ks*32 + qw*8 .. +8
    f16x8 a[2][4];
    if (F32IN) {
        const float* X = (const float*)Xv;
#pragma unroll
        for (int rf = 0; rf < 2; ++rf) {
            int row = row0 + w * 32 + rf * 16 + cl;
            row = row < NN ? row : NN - 1;      // clamp (guarded at write)
            const float* p = X + (size_t)row * DD;
#pragma unroll
            for (int ks = 0; ks < 4; ++ks) {
                float4 u0 = *(const float4*)(p + ks * 32 + qw * 8);
                float4 u1 = *(const float4*)(p + ks * 32 + qw * 8 + 4);
                f16x8 v;
                v[0] = (f16)u0.x; v[1] = (f16)u0.y; v[2] = (f16)u0.z; v[3] = (f16)u0.w;
                v[4] = (f16)u1.x; v[5] = (f16)u1.y; v[6] = (f16)u1.z; v[7] = (f16)u1.w;
                a[rf][ks] = v;
            }
        }
    } else {
        const f16* X = (const f16*)Xv;
#pragma unroll
        for (int rf = 0; rf < 2; ++rf) {
            int row = row0 + w * 32 + rf * 16 + cl;
            row = row < NN ? row : NN - 1;
            const f16* p = X + (size_t)row * DD;
#pragma unroll
            for (int ks = 0; ks < 4; ++ks)
                a[rf][ks] = *(const f16x8*)(p + ks * 32 + qw * 8);
        }
    }

    // stage W: flat copy of pre-padded image
    {
        const uint4* wsrc = (const uint4*)Wt;
        uint4* wdst = (uint4*)sW;
#pragma unroll
        for (int it = 0; it < 9; ++it) wdst[it * 256 + t] = wsrc[it * 256 + t];
    }
    __syncthreads();

    f32x4 acc[2][8] = {};
#pragma unroll
    for (int ks = 0; ks < 4; ++ks) {
        int koff = ks * 32 + qw * 8;
#pragma unroll
        for (int nf = 0; nf < 8; ++nf) {
            f16x8 bh = *(const f16x8*)(sW + (nf * 16 + cl) * LDA + koff);
            acc[0][nf] = __builtin_amdgcn_mfma_f32_16x16x32_f16(a[0][ks], bh, acc[0][nf], 0, 0, 0);
            acc[1][nf] = __builtin_amdgcn_mfma_f32_16x16x32_f16(a[1][ks], bh, acc[1][nf], 0, 0, 0);
        }
    }

    if (MODE == 0) {
        float bc[8];
#pragma unroll
        for (int nf = 0; nf < 8; ++nf) bc[nf] = bias[nf * 16 + cl];
#pragma unroll
        for (int rf = 0; rf < 2; ++rf) {
            int rbase = row0 + w * 32 + rf * 16 + qw * 4;
#pragma unroll
            for (int i = 0; i < 4; ++i) {
                int row = rbase + i;
                if (row < NN) {
#pragma unroll
                    for (int nf = 0; nf < 8; ++nf) {
                        float v = acc[rf][nf][i] + bc[nf];
                        v = v > 0.f ? v : 0.01f * v;
                        Yh[(size_t)row * DD + nf * 16 + cl] = __float2half(v);
                    }
                }
            }
        }
    } else {
        float as[8], ad[8];
#pragma unroll
        for (int nf = 0; nf < 8; ++nf) {
            as[nf] = av_src[nf * 16 + cl];
            ad[nf] = av_dst[nf * 16 + cl];
        }
#pragma unroll
        for (int rf = 0; rf < 2; ++rf) {
            int rbase = row0 + w * 32 + rf * 16 + qw * 4;
            float pa[4] = {0.f, 0.f, 0.f, 0.f}, pb[4] = {0.f, 0.f, 0.f, 0.f};
#pragma unroll
            for (int nf = 0; nf < 8; ++nf) {
#pragma unroll
                for (int i = 0; i < 4; ++i) {
                    float v = acc[rf][nf][i];
                    pa[i] += v * as[nf];
                    pb[i] += v * ad[nf];
                }
            }
#pragma unroll
            for (int i = 0; i < 4; ++i) {
                int row = rbase + i;
                if (row < NN) {
#pragma unroll
                    for (int nf = 0; nf < 8; ++nf)
                        Yh[(size_t)row * DD + nf * 16 + cl] = __float2half(acc[rf][nf][i]);
                }
            }
#pragma unroll
            for (int i = 0; i < 4; ++i) {
#pragma unroll
                for (int off = 8; off >= 1; off >>= 1) {
                    pa[i] += __shfl_xor(pa[i], off);
                    pb[i] += __shfl_xor(pb[i], off);
                }
            }
            if (cl == 0) {
#pragma unroll
                for (int i = 0; i < 4; ++i) {
                    int row = rbase + i;
                    if (row < NN) {
                        alpha_src[row] = pa[i];
                        alpha_dst[row] = pb[i];
                    }
                }
            }
        }
    }
}

// ---------------- per-edge packed (src, exp-weight) records + 16-record pad ----------------
__global__ __launch_bounds__(256) void edgew_k(const int* __restrict__ ssrc,
                                               const int* __restrict__ sdst,
                                               const float* __restrict__ alpha_src,
                                               const float* __restrict__ alpha_dst,
                                               int2* __restrict__ epk) {
    int j = blockIdx.x * 256 + threadIdx.x;
    if (j < EE) {
        int s = ssrc[j];
        float e = alpha_src[s] + alpha_dst[sdst[j]];
        e = e > 0.f ? e : 0.2f * e;
        epk[j] = make_int2(s, __float_as_int(__expf(e)));
    } else if (j < EE + 16) {
        epk[j] = make_int2(0, 0);   // pad: row 0, weight 0 (masked anyway)
    }
}

// ---------------- Per-dst aggregation + softmax-normalize + bias + LN + leaky ----------------
// one wave per dst node. Lane split: lanes 0-31 process even edges, 32-63 odd edges;
// lane owns channels 4c..4c+3 (8 B gather). Packed fp16 FMA accumulation with per-window
// f32 flush. Edge metadata via wave-uniform scalar loads.
template <int HOUT>
__global__ __launch_bounds__(256) void agg_k(const __half* __restrict__ tmp,
                                             const int2* __restrict__ epk,
                                             const int* __restrict__ offsets,
                                             const float* __restrict__ bias,
                                             const float* __restrict__ gamma,
                                             const float* __restrict__ beta,
                                             void* __restrict__ outv) {
    int wid = (blockIdx.x * 256 + threadIdx.x) >> 6;
    wid = __builtin_amdgcn_readfirstlane(wid);
    int lane = threadIdx.x & 63;
    int eh = lane >> 5;        // 0: even edges, 1: odd edges
    int c  = lane & 31;        // channel group: owns channels 4c..4c+3
    int beg = __builtin_amdgcn_readfirstlane(offsets[wid]);
    int end = __builtin_amdgcn_readfirstlane(offsets[wid + 1]);

    const char* tmpB = (const char*)tmp;
    float fx0 = 0.f, fx1 = 0.f, fx2 = 0.f, fx3 = 0.f;
    float dsum = 0.f;

    for (int j = (beg & ~1); j < end; j += 16) {
        int4 q[8];
#pragma unroll
        for (int k = 0; k < 8; ++k) q[k] = *(const int4*)(epk + j + 2 * k);
        __half2 acc01 = __float2half2_rn(0.f);
        __half2 acc23 = __float2half2_rn(0.f);
#pragma unroll
        for (int k = 0; k < 8; ++k) {
            int e0 = j + 2 * k;
            // scalar masks (s_cselect): weight = 0 for out-of-range slots
            float we = ((k == 0 ? e0 >= beg : true) && e0 < end) ? __int_as_float(q[k].y) : 0.f;
            float wo = (e0 + 1 < end) ? __int_as_float(q[k].w) : 0.f;
            int   row = eh ? q[k].z : q[k].x;
            float wv  = eh ? wo : we;
            const __half2* p = (const __half2*)(tmpB + ((size_t)(unsigned)row << 8) + (c << 3));
            __half2 h0 = p[0];
            __half2 h1 = p[1];
            dsum += wv;
            __half2 wh2 = __half2half2(__float2half(wv));
            acc01 = __hfma2(wh2, h0, acc01);
            acc23 = __hfma2(wh2, h1, acc23);
        }
        float2 f01 = __half22float2(acc01);
        float2 f23 = __half22float2(acc23);
        fx0 += f01.x; fx1 += f01.y; fx2 += f23.x; fx3 += f23.y;
    }

    // combine even/odd halves (lane l and l^32 hold the same channel group)
    fx0 += __shfl_xor(fx0, 32);
    fx1 += __shfl_xor(fx1, 32);
    fx2 += __shfl_xor(fx2, 32);
    fx3 += __shfl_xor(fx3, 32);
    dsum += __shfl_xor(dsum, 32);
    float inv = 1.0f / (dsum + 1e-16f);

    float4 bi = *(const float4*)(bias + 4 * c);
    float a0 = fx0 * inv + bi.x;
    float a1 = fx1 * inv + bi.y;
    float a2 = fx2 * inv + bi.z;
    float a3 = fx3 * inv + bi.w;

    float s1 = (a0 + a1) + (a2 + a3);
#pragma unroll
    for (int off = 16; off >= 1; off >>= 1) s1 += __shfl_xor(s1, off);
    float mu = s1 * (1.0f / 128.0f);
    float d0 = a0 - mu, d1 = a1 - mu, d2 = a2 - mu, d3 = a3 - mu;
    float s2 = (d0 * d0 + d1 * d1) + (d2 * d2 + d3 * d3);
#pragma unroll
    for (int off = 16; off >= 1; off >>= 1) s2 += __shfl_xor(s2, off);
    float rstd = rsqrtf(s2 * (1.0f / 128.0f) + 1e-5f);

    float4 g  = *(const float4*)(gamma + 4 * c);
    float4 be = *(const float4*)(beta + 4 * c);
    float y0 = d0 * rstd * g.x + be.x;
    float y1 = d1 * rstd * g.y + be.y;
    float y2 = d2 * rstd * g.z + be.z;
    float y3 = d3 * rstd * g.w + be.w;
    y0 = y0 > 0.f ? y0 : 0.01f * y0;
    y1 = y1 > 0.f ? y1 : 0.01f * y1;
    y2 = y2 > 0.f ? y2 : 0.01f * y2;
    y3 = y3 > 0.f ? y3 : 0.01f * y3;

    if (lane < 32) {
        if (HOUT) {
            union { __half2 h2[2]; uint2 u; } pk;
            pk.h2[0] = __floats2half2_rn(y0, y1);
            pk.h2[1] = __floats2half2_rn(y2, y3);
            ((uint2*)outv)[(size_t)wid * 32 + c] = pk.u;
        } else {
            ((float4*)outv)[(size_t)wid * 32 + c] = make_float4(y0, y1, y2, y3);
        }
    }
}

extern "C" void kernel_launch(void* const* d_in, const int* in_sizes, int n_in,
                              void* d_out, int out_size, void* d_ws, size_t ws_size,
                              hipStream_t stream) {
    const float* x       = (const float*)d_in[0];
    const int*   ei      = (const int*)d_in[1];
    const float* W_in    = (const float*)d_in[2];
    const float* b_in    = (const float*)d_in[3];
    const float* Wl      = (const float*)d_in[4];
    const float* att_src = (const float*)d_in[5];
    const float* att_dst = (const float*)d_in[6];
    const float* bias_l  = (const float*)d_in[7];
    const float* gamma   = (const float*)d_in[8];
    const float* beta    = (const float*)d_in[9];
    float* out = (float*)d_out;

    char* ws = (char*)d_ws;
    __half* tmp      = (__half*)ws; ws += (size_t)NN * DD * 2;   // 25.6 MB
    float* alpha_src = (float*)ws;  ws += (size_t)NN * 4;
    float* alpha_dst = (float*)ws;  ws += (size_t)NN * 4;
    int*   offsets   = (int*)ws;    ws += (size_t)(NN + 4) * 4;
    int*   ssrc      = (int*)ws;    ws += (size_t)EE * 4;        // 6.4 MB
    int*   sdst      = (int*)ws;    ws += (size_t)EE * 4;        // 6.4 MB
    int2*  ebuf      = (int2*)ws;   ws += (size_t)(EE + 16) * 8; // 12.8 MB (dead after CSR build)
    int*   bcnt      = (int*)ws;    ws += (size_t)NBUCK * NBLKP * 4;
    int*   ebase     = (int*)ws;    ws += (size_t)NBUCK * NBLKP * 4;
    int*   btot      = (int*)ws;    ws += (size_t)(NBUCK + 4) * 4;
    int*   bstart    = (int*)ws;    ws += (size_t)(NBUCK + 4) * 4;
    f16*   Wt        = (f16*)ws;    ws += (size_t)5 * WCHUNKS * 16;  // 184 KB
    int2* epk = ebuf;               // aliases ebuf: written only after bucket_sort_k

    // fp16 hidden-state buffer lives in the (not-yet-needed) d_out allocation:
    // layers 0..2 store h as fp16 in the first 25.6 MB; the final agg_k fully
    // overwrites d_out with fp32 output.
    __half* hbuf = (__half*)d_out;

    const int* esrc = ei;
    const int* edst = ei + EE;

    // bucketed CSR build (edges constant within a launch)
    part_hist_k<<<NBLKP, 256, 0, stream>>>(edst, bcnt);
    scanBB_k<<<NBUCK, 256, 0, stream>>>(bcnt, ebase, btot);
    scanBT_k<<<1, 256, 0, stream>>>(btot, bstart, offsets);
    part_k<<<NBLKP, 256, 0, stream>>>(esrc, edst, bstart, ebase, ebuf);
    bucket_sort_k<<<NBUCK, 512, 0, stream>>>(ebuf, bstart, offsets, ssrc, sdst);
    wprep_k<<<5, 256, 0, stream>>>(W_in, Wl, Wt);

    const int gg = (NN + 127) / 128;          // 782
    const int eg = (EE + 16 + 255) / 256;     // 6251 (covers pad records)

    // input projection: h0 = fp16(leaky(x @ W_in + b_in))
    gemm_k<0, 1><<<gg, 256, 0, stream>>>(x, Wt, b_in, nullptr, nullptr, hbuf, nullptr, nullptr);

    for (int i = 0; i < 4; i++) {
        gemm_k<1, 0><<<gg, 256, 0, stream>>>(hbuf, Wt + (size_t)(i + 1) * (WCHUNKS * 8), nullptr,
                                             att_src + (size_t)i * DD, att_dst + (size_t)i * DD,
                                             tmp, alpha_src, alpha_dst);
        edgew_k<<<eg, 256, 0, stream>>>(ssrc, sdst, alpha_src, alpha_dst, epk);
        if (i < 3) {
            agg_k<1><<<NN / 4, 256, 0, stream>>>(tmp, epk, offsets,
                                                 bias_l + (size_t)i * DD, gamma + (size_t)i * DD,
                                                 beta + (size_t)i * DD, (void*)hbuf);
        } else {
            agg_k<0><<<NN / 4, 256, 0, stream>>>(tmp, epk, offsets,
                                                 bias_l + (size_t)i * DD, gamma + (size_t)i * DD,
                                                 beta + (size_t)i * DD, (void*)out);
        }
    }
}

// Round 6
// 547.196 us; speedup vs baseline: 1.3496x; 1.0539x over previous
//
#include <hip/hip_runtime.h>
#include <hip/hip_fp16.h>
#include <math.h>

#define NN 100000
#define EE 1600000
#define DD 128
#define NBUCK 196          // ceil(NN / 512) buckets of 512 dst nodes
#define NBLKP 196          // partition blocks, 8192 edges each (196*8192 >= EE)
#define EPB 8192           // edges per partition block

typedef _Float16 f16;
typedef f16 f16x8 __attribute__((ext_vector_type(8)));
typedef float f32x4 __attribute__((ext_vector_type(4)));

#define LDA 136            // padded LDS row stride in halves (272 B = 17*16)
#define WCHUNKS 2304       // 36864 B per W matrix image (128*136 halves + pad)

// ---------- bucketed CSR build ----------
__global__ __launch_bounds__(256) void part_hist_k(const int* __restrict__ dst, int* __restrict__ bcnt) {
    __shared__ int lc[NBUCK];
    int t = threadIdx.x, blk = blockIdx.x;
    if (t < NBUCK) lc[t] = 0;
    __syncthreads();
    int e0 = blk * EPB;
    for (int i = t; i < EPB; i += 256) {
        int e = e0 + i;
        if (e < EE) atomicAdd(&lc[dst[e] >> 9], 1);
    }
    __syncthreads();
    if (t < NBUCK) bcnt[t * NBLKP + blk] = lc[t];
}

__global__ __launch_bounds__(256) void scanBB_k(const int* __restrict__ bcnt, int* __restrict__ ebase,
                                                int* __restrict__ btot) {
    __shared__ int sh[256];
    int t = threadIdx.x, b = blockIdx.x;
    int c = (t < NBLKP) ? bcnt[b * NBLKP + t] : 0;
    sh[t] = c;
    __syncthreads();
    for (int off = 1; off < 256; off <<= 1) {
        int v = (t >= off) ? sh[t - off] : 0;
        __syncthreads();
        sh[t] += v;
        __syncthreads();
    }
    if (t < NBLKP) ebase[b * NBLKP + t] = sh[t] - c;  // exclusive
    if (t == 255) btot[b] = sh[255];
}

__global__ __launch_bounds__(256) void scanBT_k(const int* __restrict__ btot, int* __restrict__ bstart,
                                                int* __restrict__ offsets) {
    __shared__ int sh[256];
    int t = threadIdx.x;
    int c = (t < NBUCK) ? btot[t] : 0;
    sh[t] = c;
    __syncthreads();
    for (int off = 1; off < 256; off <<= 1) {
        int v = (t >= off) ? sh[t - off] : 0;
        __syncthreads();
        sh[t] += v;
        __syncthreads();
    }
    if (t < NBUCK) bstart[t] = sh[t] - c;
    if (t == 0) { bstart[NBUCK] = EE; offsets[NN] = EE; }
}

__global__ __launch_bounds__(256) void part_k(const int* __restrict__ src, const int* __restrict__ dst,
                                              const int* __restrict__ bstart, const int* __restrict__ ebase,
                                              int2* __restrict__ ebuf) {
    __shared__ int cur[NBUCK];
    int t = threadIdx.x, blk = blockIdx.x;
    if (t < NBUCK) cur[t] = bstart[t] + ebase[t * NBLKP + blk];
    __syncthreads();
    int e0 = blk * EPB;
    for (int i = t; i < EPB; i += 256) {
        int e = e0 + i;
        if (e < EE) {
            int s = src[e], d = dst[e];
            int p = atomicAdd(&cur[d >> 9], 1);
            ebuf[p] = make_int2(s, d);
        }
    }
}

__global__ __launch_bounds__(512) void bucket_sort_k(const int2* __restrict__ ebuf,
                                                     const int* __restrict__ bstart,
                                                     int* __restrict__ offsets,
                                                     int* __restrict__ ssrc,
                                                     int* __restrict__ sdst) {
    __shared__ int sh[512];
    __shared__ int cur[512];
    int t = threadIdx.x, b = blockIdx.x;
    int d0 = b << 9;
    int beg = bstart[b], end = bstart[b + 1];

    cur[t] = 0;
    __syncthreads();
    for (int e = beg + t; e < end; e += 512) atomicAdd(&cur[ebuf[e].y - d0], 1);
    __syncthreads();
    int c = cur[t];
    sh[t] = c;
    __syncthreads();
    for (int off = 1; off < 512; off <<= 1) {
        int v = (t >= off) ? sh[t - off] : 0;
        __syncthreads();
        sh[t] += v;
        __syncthreads();
    }
    int excl = sh[t] - c;
    if (d0 + t < NN) offsets[d0 + t] = beg + excl;
    cur[t] = beg + excl;
    __syncthreads();
    for (int e = beg + t; e < end; e += 512) {
        int2 ed = ebuf[e];
        int p = atomicAdd(&cur[ed.y - d0], 1);
        ssrc[p] = ed.x;
        sdst[p] = ed.y;
    }
}

// ---------------- W prep: transpose + fp16 round into LDS-image layout; wa = W @ a ----------------
__global__ __launch_bounds__(256) void wprep_k(const float* __restrict__ W_in,
                                               const float* __restrict__ Wl,
                                               const float* __restrict__ att_src,
                                               const float* __restrict__ att_dst,
                                               f16* __restrict__ Wt,
                                               float* __restrict__ wav) {
    int m = blockIdx.x;  // 0..4
    const float* src = (m == 0) ? W_in : (Wl + (size_t)(m - 1) * DD * DD);
    f16* dst = Wt + (size_t)m * (WCHUNKS * 8);
    for (int q = 0; q < 64; ++q) {
        int idx = q * 256 + threadIdx.x;   // 0..16383  (= k*128 + n)
        int k = idx >> 7, n = idx & 127;
        dst[n * LDA + k] = (f16)src[idx];
    }
    if (m >= 1) {
        // wa[k] = sum_n W[k][n] * a[n]  (exact f32; alpha = h . wa == (h@W) . a)
        int t = threadIdx.x;
        const float* av = (t < 128) ? (att_src + (size_t)(m - 1) * DD)
                                    : (att_dst + (size_t)(m - 1) * DD);
        int k = t & 127;
        float s = 0.f;
        for (int n = 0; n < 128; ++n) s += src[k * 128 + n] * av[n];
        wav[(size_t)(m - 1) * 256 + (t >> 7) * 128 + k] = s;
    }
}

// ---------------- GEMM: tmp = h @ W via fp16 MFMA + input-side alpha dots ----------------
// BM=128 per block, 256 threads = 4 waves, each wave 32 rows x 128 cols.
// A fragments loaded directly global->VGPR; W staged in LDS (36 KB).
// FUSED=1 (layer 0): h0 = fp16(leaky(x@W_in + b)) computed in-reg, routed via LDS to
//   become A of the second MFMA chain (h0 never touches HBM); Wt1 = Wl_0 image.
// Output tmp stored via LDS transpose -> fully coalesced 16 B stores.
// alpha_src/dst computed from the h fragments with precomputed wa vectors.
template <int FUSED>
__global__ __launch_bounds__(256, 2) void gemm_k(const void* __restrict__ Xv,
                                                 const f16* __restrict__ Wt0,
                                                 const f16* __restrict__ Wt1,
                                                 const float* __restrict__ bias,
                                                 const float* __restrict__ wa_s,
                                                 const float* __restrict__ wa_d,
                                                 __half* __restrict__ Yh,
                                                 float* __restrict__ alpha_src,
                                                 float* __restrict__ alpha_dst) {
    __shared__ __align__(16) f16 sW[WCHUNKS * 8];      // 36864 B
    __shared__ __align__(16) f16 sOut[4][32][LDA];     // 34816 B, padded rows (bank-safe)
    int t = threadIdx.x;
    int w = t >> 6, lane = t & 63;
    int cl = lane & 15, qw = lane >> 4;
    int row0 = blockIdx.x * 128;

    // A fragments: row = row0 + w*32 + rf*16 + cl, k-span = ks*32 + qw*8 .. +8
    f16x8 a[2][4];
    if (FUSED) {
        const float* X = (const float*)Xv;
#pragma unroll
        for (int rf = 0; rf < 2; ++rf) {
            int row = row0 + w * 32 + rf * 16 + cl;
            row = row < NN ? row : NN - 1;      // clamp (guarded at write)
            const float* p = X + (size_t)row * DD;
#pragma unroll
            for (int ks = 0; ks < 4; ++ks) {
                float4 u0 = *(const float4*)(p + ks * 32 + qw * 8);
                float4 u1 = *(const float4*)(p + ks * 32 + qw * 8 + 4);
                f16x8 v;
                v[0] = (f16)u0.x; v[1] = (f16)u0.y; v[2] = (f16)u0.z; v[3] = (f16)u0.w;
                v[4] = (f16)u1.x; v[5] = (f16)u1.y; v[6] = (f16)u1.z; v[7] = (f16)u1.w;
                a[rf][ks] = v;
            }
        }
    } else {
        const f16* X = (const f16*)Xv;
#pragma unroll
        for (int rf = 0; rf < 2; ++rf) {
            int row = row0 + w * 32 + rf * 16 + cl;
            row = row < NN ? row : NN - 1;
            const f16* p = X + (size_t)row * DD;
#pragma unroll
            for (int ks = 0; ks < 4; ++ks)
                a[rf][ks] = *(const f16x8*)(p + ks * 32 + qw * 8);
        }
    }

    // stage W image
    {
        const uint4* wsrc = (const uint4*)Wt0;
        uint4* wdst = (uint4*)sW;
#pragma unroll
        for (int it = 0; it < 9; ++it) wdst[it * 256 + t] = wsrc[it * 256 + t];
    }
    __syncthreads();

    f32x4 acc[2][8] = {};
#pragma unroll
    for (int ks = 0; ks < 4; ++ks) {
        int koff = ks * 32 + qw * 8;
#pragma unroll
        for (int nf = 0; nf < 8; ++nf) {
            f16x8 bh = *(const f16x8*)(sW + (nf * 16 + cl) * LDA + koff);
            acc[0][nf] = __builtin_amdgcn_mfma_f32_16x16x32_f16(a[0][ks], bh, acc[0][nf], 0, 0, 0);
            acc[1][nf] = __builtin_amdgcn_mfma_f32_16x16x32_f16(a[1][ks], bh, acc[1][nf], 0, 0, 0);
        }
    }

    if (FUSED) {
        __syncthreads();   // all waves done reading W_in image
        // restage W with Wl_0 image
        {
            const uint4* wsrc = (const uint4*)Wt1;
            uint4* wdst = (uint4*)sW;
#pragma unroll
            for (int it = 0; it < 9; ++it) wdst[it * 256 + t] = wsrc[it * 256 + t];
        }
        // h0 = leaky(acc + bias) -> own wave's sOut region (fp16)
        float bc[8];
#pragma unroll
        for (int nf = 0; nf < 8; ++nf) bc[nf] = bias[nf * 16 + cl];
#pragma unroll
        for (int rf = 0; rf < 2; ++rf)
#pragma unroll
            for (int i = 0; i < 4; ++i)
#pragma unroll
                for (int nf = 0; nf < 8; ++nf) {
                    float v = acc[rf][nf][i] + bc[nf];
                    v = v > 0.f ? v : 0.01f * v;
                    sOut[w][rf * 16 + qw * 4 + i][nf * 16 + cl] = (f16)v;
                }
        __syncthreads();   // Wl_0 image staged
        // reload A fragments from h0 tile (within-wave LDS dependency)
#pragma unroll
        for (int rf = 0; rf < 2; ++rf)
#pragma unroll
            for (int ks = 0; ks < 4; ++ks)
                a[rf][ks] = *(const f16x8*)&sOut[w][rf * 16 + cl][ks * 32 + qw * 8];
        // second MFMA chain: tmp = h0 @ Wl_0
#pragma unroll
        for (int rf = 0; rf < 2; ++rf)
#pragma unroll
            for (int nf = 0; nf < 8; ++nf)
                acc[rf][nf] = (f32x4){0.f, 0.f, 0.f, 0.f};
#pragma unroll
        for (int ks = 0; ks < 4; ++ks) {
            int koff = ks * 32 + qw * 8;
#pragma unroll
            for (int nf = 0; nf < 8; ++nf) {
                f16x8 bh = *(const f16x8*)(sW + (nf * 16 + cl) * LDA + koff);
                acc[0][nf] = __builtin_amdgcn_mfma_f32_16x16x32_f16(a[0][ks], bh, acc[0][nf], 0, 0, 0);
                acc[1][nf] = __builtin_amdgcn_mfma_f32_16x16x32_f16(a[1][ks], bh, acc[1][nf], 0, 0, 0);
            }
        }
    }

    // ---- alpha dots from input-side fragments: alpha = h . wa ----
#pragma unroll
    for (int rf = 0; rf < 2; ++rf) {
        float pa = 0.f, pb = 0.f;
#pragma unroll
        for (int ks = 0; ks < 4; ++ks) {
            const float* ps = wa_s + ks * 32 + qw * 8;
            const float* pd = wa_d + ks * 32 + qw * 8;
            float4 s0 = *(const float4*)ps, s1 = *(const float4*)(ps + 4);
            float4 d0 = *(const float4*)pd, d1 = *(const float4*)(pd + 4);
            float sv[8] = {s0.x, s0.y, s0.z, s0.w, s1.x, s1.y, s1.z, s1.w};
            float dv[8] = {d0.x, d0.y, d0.z, d0.w, d1.x, d1.y, d1.z, d1.w};
#pragma unroll
            for (int e = 0; e < 8; ++e) {
                float f = (float)a[rf][ks][e];
                pa = fmaf(f, sv[e], pa);
                pb = fmaf(f, dv[e], pb);
            }
        }
        pa += __shfl_xor(pa, 16); pa += __shfl_xor(pa, 32);
        pb += __shfl_xor(pb, 16); pb += __shfl_xor(pb, 32);
        if (qw == 0) {
            int row = row0 + w * 32 + rf * 16 + cl;
            if (row < NN) {
                alpha_src[row] = pa;
                alpha_dst[row] = pb;
            }
        }
    }

    // ---- tmp store via LDS transpose (coalesced 16 B stores) ----
#pragma unroll
    for (int rf = 0; rf < 2; ++rf)
#pragma unroll
        for (int i = 0; i < 4; ++i)
#pragma unroll
            for (int nf = 0; nf < 8; ++nf)
                sOut[w][rf * 16 + qw * 4 + i][nf * 16 + cl] = (f16)acc[rf][nf][i];
#pragma unroll
    for (int p = 0; p < 8; ++p) {
        int rl = p * 4 + qw;
        uint4 v = *(const uint4*)&sOut[w][rl][cl * 8];
        int row = row0 + w * 32 + rl;
        if (row < NN) *(uint4*)(Yh + (size_t)row * DD + cl * 8) = v;
    }
}

// ---------------- per-edge packed (src, exp-weight) records + 16-record pad ----------------
__global__ __launch_bounds__(256) void edgew_k(const int* __restrict__ ssrc,
                                               const int* __restrict__ sdst,
                                               const float* __restrict__ alpha_src,
                                               const float* __restrict__ alpha_dst,
                                               int2* __restrict__ epk) {
    int j = blockIdx.x * 256 + threadIdx.x;
    if (j < EE) {
        int s = ssrc[j];
        float e = alpha_src[s] + alpha_dst[sdst[j]];
        e = e > 0.f ? e : 0.2f * e;
        epk[j] = make_int2(s, __float_as_int(__expf(e)));
    } else if (j < EE + 16) {
        epk[j] = make_int2(0, 0);   // pad: row 0, weight 0 (masked anyway)
    }
}

// ---------------- Per-dst aggregation + softmax-normalize + bias + LN + leaky ----------------
// one wave per dst node; lane c owns channels 2c, 2c+1 (R4 form: best measured, 67 us).
// Edge metadata via wave-uniform scalar loads; fixed 16-wide masked window.
template <int HOUT>
__global__ __launch_bounds__(256) void agg_k(const __half* __restrict__ tmp,
                                             const int2* __restrict__ epk,
                                             const int* __restrict__ offsets,
                                             const float* __restrict__ bias,
                                             const float* __restrict__ gamma,
                                             const float* __restrict__ beta,
                                             void* __restrict__ outv) {
    int wid = (blockIdx.x * 256 + threadIdx.x) >> 6;
    wid = __builtin_amdgcn_readfirstlane(wid);
    int lane = threadIdx.x & 63;
    int beg = __builtin_amdgcn_readfirstlane(offsets[wid]);
    int end = __builtin_amdgcn_readfirstlane(offsets[wid + 1]);

    const __half2* tmp2 = (const __half2*)tmp;
    float ax0 = 0.f, ay0 = 0.f, ax1 = 0.f, ay1 = 0.f, dsum = 0.f;

    for (int j = (beg & ~1); j < end; j += 16) {
        int4 q[8];
#pragma unroll
        for (int k = 0; k < 8; ++k) q[k] = *(const int4*)(epk + j + 2 * k);
        __half2 h[16];
#pragma unroll
        for (int k = 0; k < 8; ++k) {
            h[2 * k]     = tmp2[(size_t)q[k].x * 64 + lane];
            h[2 * k + 1] = tmp2[(size_t)q[k].z * 64 + lane];
        }
#pragma unroll
        for (int k = 0; k < 8; ++k) {
            int e0 = j + 2 * k, e1 = e0 + 1;
            bool v0 = (k == 0) ? (e0 >= beg && e0 < end) : (e0 < end);
            bool v1 = (e1 < end);
            float w0 = v0 ? __int_as_float(q[k].y) : 0.f;
            float w1 = v1 ? __int_as_float(q[k].w) : 0.f;
            dsum += w0 + w1;
            ax0 = fmaf(w0, __half2float(h[2 * k].x), ax0);
            ay0 = fmaf(w0, __half2float(h[2 * k].y), ay0);
            ax1 = fmaf(w1, __half2float(h[2 * k + 1].x), ax1);
            ay1 = fmaf(w1, __half2float(h[2 * k + 1].y), ay1);
        }
    }

    // dsum is lane-uniform: no cross-lane reduction needed
    float inv = 1.0f / (dsum + 1e-16f);

    float ax = (ax0 + ax1) * inv + bias[2 * lane];
    float ay = (ay0 + ay1) * inv + bias[2 * lane + 1];

    float s1 = ax + ay;
#pragma unroll
    for (int off = 32; off >= 1; off >>= 1) s1 += __shfl_xor(s1, off);
    float mu = s1 * (1.0f / 128.0f);
    float dx = ax - mu, dy = ay - mu;
    float s2 = dx * dx + dy * dy;
#pragma unroll
    for (int off = 32; off >= 1; off >>= 1) s2 += __shfl_xor(s2, off);
    float rstd = rsqrtf(s2 * (1.0f / 128.0f) + 1e-5f);

    float yx = dx * rstd * gamma[2 * lane] + beta[2 * lane];
    float yy = dy * rstd * gamma[2 * lane + 1] + beta[2 * lane + 1];
    yx = yx > 0.f ? yx : 0.01f * yx;
    yy = yy > 0.f ? yy : 0.01f * yy;
    if (HOUT) {
        ((__half2*)outv)[(size_t)wid * 64 + lane] = __floats2half2_rn(yx, yy);
    } else {
        ((float2*)outv)[(size_t)wid * 64 + lane] = make_float2(yx, yy);
    }
}

extern "C" void kernel_launch(void* const* d_in, const int* in_sizes, int n_in,
                              void* d_out, int out_size, void* d_ws, size_t ws_size,
                              hipStream_t stream) {
    const float* x       = (const float*)d_in[0];
    const int*   ei      = (const int*)d_in[1];
    const float* W_in    = (const float*)d_in[2];
    const float* b_in    = (const float*)d_in[3];
    const float* Wl      = (const float*)d_in[4];
    const float* att_src = (const float*)d_in[5];
    const float* att_dst = (const float*)d_in[6];
    const float* bias_l  = (const float*)d_in[7];
    const float* gamma   = (const float*)d_in[8];
    const float* beta    = (const float*)d_in[9];
    float* out = (float*)d_out;

    char* ws = (char*)d_ws;
    __half* tmp      = (__half*)ws; ws += (size_t)NN * DD * 2;   // 25.6 MB
    float* alpha_src = (float*)ws;  ws += (size_t)NN * 4;
    float* alpha_dst = (float*)ws;  ws += (size_t)NN * 4;
    int*   offsets   = (int*)ws;    ws += (size_t)(NN + 4) * 4;
    int*   ssrc      = (int*)ws;    ws += (size_t)EE * 4;        // 6.4 MB
    int*   sdst      = (int*)ws;    ws += (size_t)EE * 4;        // 6.4 MB
    int2*  ebuf      = (int2*)ws;   ws += (size_t)(EE + 16) * 8; // 12.8 MB (dead after CSR build)
    int*   bcnt      = (int*)ws;    ws += (size_t)NBUCK * NBLKP * 4;
    int*   ebase     = (int*)ws;    ws += (size_t)NBUCK * NBLKP * 4;
    int*   btot      = (int*)ws;    ws += (size_t)(NBUCK + 4) * 4;
    int*   bstart    = (int*)ws;    ws += (size_t)(NBUCK + 4) * 4;
    f16*   Wt        = (f16*)ws;    ws += (size_t)5 * WCHUNKS * 16;  // 184 KB
    float* wav       = (float*)ws;  ws += (size_t)4 * 256 * 4;       // 4 KB (wa vectors)
    int2* epk = ebuf;               // aliases ebuf: written only after bucket_sort_k

    // fp16 hidden-state buffer lives in the (not-yet-needed) d_out allocation:
    // layers 0..2 store h as fp16 in the first 25.6 MB; the final agg_k fully
    // overwrites d_out with fp32 output.
    __half* hbuf = (__half*)d_out;

    const int* esrc = ei;
    const int* edst = ei + EE;

    // bucketed CSR build (edges constant within a launch)
    part_hist_k<<<NBLKP, 256, 0, stream>>>(edst, bcnt);
    scanBB_k<<<NBUCK, 256, 0, stream>>>(bcnt, ebase, btot);
    scanBT_k<<<1, 256, 0, stream>>>(btot, bstart, offsets);
    part_k<<<NBLKP, 256, 0, stream>>>(esrc, edst, bstart, ebase, ebuf);
    bucket_sort_k<<<NBUCK, 512, 0, stream>>>(ebuf, bstart, offsets, ssrc, sdst);
    wprep_k<<<5, 256, 0, stream>>>(W_in, Wl, att_src, att_dst, Wt, wav);

    const int gg = (NN + 127) / 128;          // 782
    const int eg = (EE + 16 + 255) / 256;     // 6251 (covers pad records)

    // layer 0: fused  tmp = (leaky(x@W_in + b)) @ Wl_0  + alpha_0  (h0 never hits HBM)
    gemm_k<1><<<gg, 256, 0, stream>>>(x, Wt, Wt + (size_t)1 * (WCHUNKS * 8), b_in,
                                      wav, wav + 128, tmp, alpha_src, alpha_dst);
    edgew_k<<<eg, 256, 0, stream>>>(ssrc, sdst, alpha_src, alpha_dst, epk);
    agg_k<1><<<NN / 4, 256, 0, stream>>>(tmp, epk, offsets, bias_l, gamma, beta, (void*)hbuf);

    for (int i = 1; i < 4; i++) {
        gemm_k<0><<<gg, 256, 0, stream>>>(hbuf, Wt + (size_t)(i + 1) * (WCHUNKS * 8), nullptr, nullptr,
                                          wav + (size_t)i * 256, wav + (size_t)i * 256 + 128,
                                          tmp, alpha_src, alpha_dst);
        edgew_k<<<eg, 256, 0, stream>>>(ssrc, sdst, alpha_src, alpha_dst, epk);
        if (i < 3) {
            agg_k<1><<<NN / 4, 256, 0, stream>>>(tmp, epk, offsets,
                                                 bias_l + (size_t)i * DD, gamma + (size_t)i * DD,
                                                 beta + (size_t)i * DD, (void*)hbuf);
        } else {
            agg_k<0><<<NN / 4, 256, 0, stream>>>(tmp, epk, offsets,
                                                 bias_l + (size_t)i * DD, gamma + (size_t)i * DD,
                                                 beta + (size_t)i * DD, (void*)out);
        }
    }
}